// Round 1
// baseline (473.578 us; speedup 1.0000x reference)
//
#include <hip/hip_runtime.h>

// Poisson composition via real DCT/DST algebra (all 512-point, fp32).
//
// Math (H=W=512, Mc[u][i]=cos(pi*u*(i+.5)/512), Ms[u][i]=sin(pi*u*(i+.5)/512)):
//   gx = t * G,  gy = G^T * t,   G = Mc^T * Msw,  Msw[v][j] = -(2*pi*v/512^2)*Ms[v][j]
//   composite: gx = (1-m)*gx_t + m*gx_s  (same gy)
//   Gx = Mc * gx * Ms^T ; Gy = Ms * gy * Mc^T
//   n'[u,v] = eps_u*eps_v/(512^2) * (pi/512)*(v*Gx + u*Gy) / (1e-10 - pi^2*(u^2+v^2)/512^2)
//   res = (Mc^T * n') * Mc
//   out = res + (mean1[0,c] - mean2[0,c]) over unmasked region.
// All Nyquist (u=512 / v=512) terms cancel exactly (verified by symmetry pairing).

#define CH 262144   // 512*512
#define NCH 6       // B*C = 2*3

static constexpr float kPi       = 3.14159265358979323846f;
static constexpr float kPiOver512 = 0.006135923151542565f;          // pi/512
static constexpr float kPi2Norm  = 3.7649933338155804e-05f;         // pi^2/512^2
static constexpr float kInvHW    = 3.814697265625e-06f;             // 1/512^2

// ---------------- tables ----------------
__global__ void build_tables(float* Mc, float* Ms, float* McT, float* MsT, float* Msw) {
    int idx = blockIdx.x * blockDim.x + threadIdx.x;
    if (idx >= CH) return;
    int u = idx >> 9, i = idx & 511;
    // angle = pi*u*(2i+1)/1024, reduced exactly mod 2*pi via integer mod 2048
    int p = (u * (2 * i + 1)) & 2047;
    float ang = (float)p * (kPi / 1024.0f);
    float sv, cv;
    sincosf(ang, &sv, &cv);
    Mc [u * 512 + i] = cv;
    Ms [u * 512 + i] = sv;
    McT[i * 512 + u] = cv;
    MsT[i * 512 + u] = sv;
    Msw[u * 512 + i] = (-2.0f * kPi * (float)u * kInvHW) * sv;
}

// ---------------- transpose (for G^T) ----------------
__global__ void transpose512(const float* __restrict__ A, float* __restrict__ B) {
    __shared__ float tile[32][33];
    int bx = blockIdx.x * 32, by = blockIdx.y * 32;
    int tx = threadIdx.x & 31, ty = threadIdx.x >> 5;   // 256 threads
    for (int r = ty; r < 32; r += 8)
        tile[r][tx] = A[(by + r) * 512 + bx + tx];
    __syncthreads();
    for (int r = ty; r < 32; r += 8)
        B[(bx + r) * 512 + by + tx] = tile[tx][r];
}

// ---------------- batched 512x512x512 fp32 GEMM (NN), C = A*B ----------------
__global__ __launch_bounds__(256) void gemm_nn(const float* __restrict__ A,
                                               const float* __restrict__ B,
                                               float* __restrict__ C,
                                               int strideA, int strideB, int strideC) {
    int z = blockIdx.z;
    A += (size_t)z * strideA;
    B += (size_t)z * strideB;
    C += (size_t)z * strideC;

    __shared__ float As[16][68];   // [k][m], padded
    __shared__ float Bs[16][68];   // [k][n], padded

    int tid = threadIdx.x;
    int tx = tid & 15, ty = tid >> 4;
    int m0 = blockIdx.y * 64, n0 = blockIdx.x * 64;

    int ar = tid >> 2;            // 0..63 (row within A tile)
    int ac = (tid & 3) << 2;      // 0,4,8,12 (k within chunk)
    int br = tid >> 4;            // 0..15 (k row of B tile)
    int bc = (tid & 15) << 2;     // 0..60 (col within B tile)

    const float* Aptr = A + (size_t)(m0 + ar) * 512 + ac;
    const float* Bptr = B + (size_t)br * 512 + n0 + bc;

    float acc[4][4] = {};

    for (int k0 = 0; k0 < 512; k0 += 16) {
        float4 av = *(const float4*)(Aptr + k0);
        float4 bv = *(const float4*)(Bptr + (size_t)k0 * 512);
        As[ac + 0][ar] = av.x;
        As[ac + 1][ar] = av.y;
        As[ac + 2][ar] = av.z;
        As[ac + 3][ar] = av.w;
        *(float4*)&Bs[br][bc] = bv;
        __syncthreads();
#pragma unroll
        for (int k = 0; k < 16; ++k) {
            float4 a4 = *(const float4*)&As[k][ty << 2];
            float4 b4 = *(const float4*)&Bs[k][tx << 2];
            float a[4] = {a4.x, a4.y, a4.z, a4.w};
            float b[4] = {b4.x, b4.y, b4.z, b4.w};
#pragma unroll
            for (int i = 0; i < 4; ++i)
#pragma unroll
                for (int j = 0; j < 4; ++j)
                    acc[i][j] = fmaf(a[i], b[j], acc[i][j]);
        }
        __syncthreads();
    }

#pragma unroll
    for (int i = 0; i < 4; ++i) {
        float4 o = make_float4(acc[i][0], acc[i][1], acc[i][2], acc[i][3]);
        *(float4*)&C[(size_t)(m0 + (ty << 2) + i) * 512 + n0 + (tx << 2)] = o;
    }
}

// ---------------- composite gradients with mask ----------------
__global__ void composite(const float* __restrict__ mask,
                          float* __restrict__ gx_t, const float* __restrict__ gx_s,
                          float* __restrict__ gy_t, const float* __restrict__ gy_s,
                          int n) {
    for (int idx = blockIdx.x * blockDim.x + threadIdx.x; idx < n; idx += gridDim.x * blockDim.x) {
        float m = mask[idx];
        float om = 1.0f - m;
        gx_t[idx] = om * gx_t[idx] + m * gx_s[idx];
        gy_t[idx] = om * gy_t[idx] + m * gy_s[idx];
    }
}

// ---------------- Poisson frequency-domain solve (pointwise) ----------------
__global__ void napply(const float* __restrict__ Gx, const float* __restrict__ Gy,
                       float* __restrict__ n_out, int n) {
    for (int idx = blockIdx.x * blockDim.x + threadIdx.x; idx < n; idx += gridDim.x * blockDim.x) {
        int r = idx & (CH - 1);
        int u = r >> 9, v = r & 511;
        float num = kPiOver512 * ((float)v * Gx[idx] + (float)u * Gy[idx]);
        float den = 1e-10f - kPi2Norm * (float)(u * u + v * v);
        float eps = (u ? 2.0f : 1.0f) * (v ? 2.0f : 1.0f) * kInvHW;
        n_out[idx] = eps * num / den;   // u=v=0: num==0 exactly -> 0 (DC zeroed)
    }
}

// ---------------- per-channel sums for mean matching ----------------
__global__ __launch_bounds__(1024) void reduce_sums(const float* __restrict__ t,
                                                    const float* __restrict__ mask,
                                                    const float* __restrict__ res,
                                                    float* __restrict__ sums) {
    int z = blockIdx.x;   // 0..5
    const float* tz = t    + (size_t)z * CH;
    const float* mz = mask + (size_t)z * CH;
    const float* rz = res  + (size_t)z * CH;
    float si = 0.f, st = 0.f, sr = 0.f;
    for (int i = threadIdx.x; i < CH; i += 1024) {
        float inv = 1.0f - mz[i];
        si += inv;
        st += tz[i] * inv;
        sr += rz[i] * inv;
    }
    __shared__ float red[3 * 1024];
    red[threadIdx.x]         = si;
    red[1024 + threadIdx.x]  = st;
    red[2048 + threadIdx.x]  = sr;
    __syncthreads();
    for (int s = 512; s > 0; s >>= 1) {
        if ((int)threadIdx.x < s) {
            red[threadIdx.x]        += red[threadIdx.x + s];
            red[1024 + threadIdx.x] += red[1024 + threadIdx.x + s];
            red[2048 + threadIdx.x] += red[2048 + threadIdx.x + s];
        }
        __syncthreads();
    }
    if (threadIdx.x == 0) {
        sums[z * 3 + 0] = red[0];
        sums[z * 3 + 1] = red[1024];
        sums[z * 3 + 2] = red[2048];
    }
}

// ---------------- final: res + (mean1[0,c] - mean2[0,c]) ----------------
__global__ void final_out(const float* __restrict__ res, const float* __restrict__ sums,
                          float* __restrict__ out, int n) {
    for (int idx = blockIdx.x * blockDim.x + threadIdx.x; idx < n; idx += gridDim.x * blockDim.x) {
        int z = idx / CH;      // channel 0..5
        int c = z % 3;         // batch-0 channel index (z==c for batch 0)
        float denom = sums[c * 3 + 0];
        float m1 = sums[c * 3 + 1] / denom;
        float m2 = sums[c * 3 + 2] / denom;
        out[idx] = res[idx] + (m1 - m2);
    }
}

extern "C" void kernel_launch(void* const* d_in, const int* in_sizes, int n_in,
                              void* d_out, int out_size, void* d_ws, size_t ws_size,
                              hipStream_t stream) {
    const float* t = (const float*)d_in[0];
    const float* s = (const float*)d_in[1];
    const float* m = (const float*)d_in[2];
    float* out = (float*)d_out;
    float* F = (float*)d_ws;

    const int S = CH;
    // layout: 7 matrices + 4 per-channel buffer banks (6 channels each) + sums
    if (ws_size < (size_t)(31 * CH + 64) * sizeof(float)) return;

    float* Mc  = F + 0 * S;
    float* Ms  = F + 1 * S;
    float* McT = F + 2 * S;
    float* MsT = F + 3 * S;
    float* Msw = F + 4 * S;
    float* G   = F + 5 * S;
    float* GT  = F + 6 * S;
    float* B0  = F + 7  * S;   // [6][CH]
    float* B1  = F + 13 * S;
    float* B2  = F + 19 * S;
    float* B3  = F + 25 * S;
    float* sums = F + 31 * S;  // [6][3]

    const int NTOT = NCH * CH;

    build_tables<<<1024, 256, 0, stream>>>(Mc, Ms, McT, MsT, Msw);

    // G = Mc^T * Msw ; GT = G^T
    gemm_nn<<<dim3(8, 8, 1), 256, 0, stream>>>(McT, Msw, G, 0, 0, 0);
    transpose512<<<dim3(16, 16), 256, 0, stream>>>(G, GT);

    // gradients: gx_t=B0, gx_s=B1, gy_t=B2, gy_s=B3
    gemm_nn<<<dim3(8, 8, NCH), 256, 0, stream>>>(t,  G,  B0, S, 0, S);
    gemm_nn<<<dim3(8, 8, NCH), 256, 0, stream>>>(s,  G,  B1, S, 0, S);
    gemm_nn<<<dim3(8, 8, NCH), 256, 0, stream>>>(GT, t,  B2, 0, S, S);
    gemm_nn<<<dim3(8, 8, NCH), 256, 0, stream>>>(GT, s,  B3, 0, S, S);

    // composite into B0 (gx), B2 (gy)
    composite<<<2048, 256, 0, stream>>>(m, B0, B1, B2, B3, NTOT);

    // Gx = Mc*gx*Ms^T -> B3 ; Gy = Ms*gy*Mc^T -> B2
    gemm_nn<<<dim3(8, 8, NCH), 256, 0, stream>>>(Mc, B0, B1, 0, S, S);   // P = Mc*gx
    gemm_nn<<<dim3(8, 8, NCH), 256, 0, stream>>>(B1, MsT, B3, S, 0, S);  // Gx
    gemm_nn<<<dim3(8, 8, NCH), 256, 0, stream>>>(Ms, B2, B0, 0, S, S);   // Q = Ms*gy
    gemm_nn<<<dim3(8, 8, NCH), 256, 0, stream>>>(B0, McT, B2, S, 0, S);  // Gy

    // n' -> B0
    napply<<<2048, 256, 0, stream>>>(B3, B2, B0, NTOT);

    // res = (Mc^T * n') * Mc -> B3
    gemm_nn<<<dim3(8, 8, NCH), 256, 0, stream>>>(McT, B0, B1, 0, S, S);
    gemm_nn<<<dim3(8, 8, NCH), 256, 0, stream>>>(B1, Mc, B3, S, 0, S);

    // mean matching
    reduce_sums<<<NCH, 1024, 0, stream>>>(t, m, B3, sums);
    final_out<<<2048, 256, 0, stream>>>(B3, sums, out, NTOT);
}

// Round 2
// 372.090 us; speedup vs baseline: 1.2728x; 1.2728x over previous
//
#include <hip/hip_runtime.h>

// Poisson composition via real DCT/DST algebra (512-point, fp32).
// res = t - mean(t) + Solve(m .* grad(s-t));  out = t + u + shift[z]
// where shift[z] = -mean_t[z] + mean_t[c] - wmean_u[c], c = z%3 (batch-0 stats).

#define CH 262144   // 512*512
#define NCH 6       // B*C
#define NTOT (NCH*CH)

static constexpr float kPi        = 3.14159265358979323846f;
static constexpr float kPiOver512 = 0.006135923151542565f;   // pi/512
static constexpr float kPi2Norm   = 3.7649933338155804e-05f; // pi^2/512^2
static constexpr float kInvHW     = 3.814697265625e-06f;     // 1/512^2

// ---------------- tables ----------------
__global__ void build_tables(float* Mc, float* Ms, float* McT, float* MsT, float* Msw) {
    int idx = blockIdx.x * blockDim.x + threadIdx.x;
    if (idx >= CH) return;
    int u = idx >> 9, i = idx & 511;
    int p = (u * (2 * i + 1)) & 2047;          // exact angle reduction mod 2pi
    float ang = (float)p * (kPi / 1024.0f);
    float sv, cv;
    sincosf(ang, &sv, &cv);
    Mc [u * 512 + i] = cv;
    Ms [u * 512 + i] = sv;
    McT[i * 512 + u] = cv;
    MsT[i * 512 + u] = sv;
    Msw[u * 512 + i] = (-2.0f * kPi * (float)u * kInvHW) * sv;
}

// ---------------- transpose ----------------
__global__ void transpose512(const float* __restrict__ A, float* __restrict__ B) {
    __shared__ float tile[32][33];
    int bx = blockIdx.x * 32, by = blockIdx.y * 32;
    int tx = threadIdx.x & 31, ty = threadIdx.x >> 5;
    for (int r = ty; r < 32; r += 8)
        tile[r][tx] = A[(by + r) * 512 + bx + tx];
    __syncthreads();
    for (int r = ty; r < 32; r += 8)
        B[(bx + r) * 512 + by + tx] = tile[tx][r];
}

// ---------------- dual-op batched 512^3 fp32 GEMM (NN), double-buffered ----------------
__global__ __launch_bounds__(256) void gemm_dual(
    const float* __restrict__ A0, int sA0, const float* __restrict__ B0p, int sB0,
    float* __restrict__ C0p, int sC0,
    const float* __restrict__ A1, int sA1, const float* __restrict__ B1p, int sB1,
    float* __restrict__ C1p, int sC1,
    int zsplit) {
    int z = blockIdx.z;
    const float* A; const float* B; float* C;
    if (z < zsplit) {
        A = A0 + (size_t)z * sA0; B = B0p + (size_t)z * sB0; C = C0p + (size_t)z * sC0;
    } else {
        int zz = z - zsplit;
        A = A1 + (size_t)zz * sA1; B = B1p + (size_t)zz * sB1; C = C1p + (size_t)zz * sC1;
    }

    __shared__ float As[2][16][68];   // [buf][k][m] padded
    __shared__ float Bs[2][16][68];   // [buf][k][n] padded

    int tid = threadIdx.x;
    int tx = tid & 15, ty = tid >> 4;
    int m0 = blockIdx.y * 64, n0 = blockIdx.x * 64;

    int ar = tid >> 2;            // 0..63
    int ac = (tid & 3) << 2;      // 0,4,8,12
    int br = tid >> 4;            // 0..15
    int bc = (tid & 15) << 2;     // 0..60

    const float* Aptr = A + (size_t)(m0 + ar) * 512 + ac;
    const float* Bptr = B + (size_t)br * 512 + n0 + bc;

    float acc[4][4] = {};

    float4 av = *(const float4*)(Aptr);
    float4 bv = *(const float4*)(Bptr);
    As[0][ac + 0][ar] = av.x; As[0][ac + 1][ar] = av.y;
    As[0][ac + 2][ar] = av.z; As[0][ac + 3][ar] = av.w;
    *(float4*)&Bs[0][br][bc] = bv;
    __syncthreads();

#pragma unroll 2
    for (int c = 0; c < 32; ++c) {
        int buf = c & 1;
        bool more = (c + 1) < 32;
        if (more) {
            av = *(const float4*)(Aptr + (c + 1) * 16);
            bv = *(const float4*)(Bptr + (size_t)((c + 1) * 16) * 512);
        }
#pragma unroll
        for (int k = 0; k < 16; ++k) {
            float4 a4 = *(const float4*)&As[buf][k][ty << 2];
            float4 b4 = *(const float4*)&Bs[buf][k][tx << 2];
            float a[4] = {a4.x, a4.y, a4.z, a4.w};
            float b[4] = {b4.x, b4.y, b4.z, b4.w};
#pragma unroll
            for (int i = 0; i < 4; ++i)
#pragma unroll
                for (int j = 0; j < 4; ++j)
                    acc[i][j] = fmaf(a[i], b[j], acc[i][j]);
        }
        if (more) {
            int nb = buf ^ 1;
            As[nb][ac + 0][ar] = av.x; As[nb][ac + 1][ar] = av.y;
            As[nb][ac + 2][ar] = av.z; As[nb][ac + 3][ar] = av.w;
            *(float4*)&Bs[nb][br][bc] = bv;
        }
        __syncthreads();
    }

#pragma unroll
    for (int i = 0; i < 4; ++i) {
        float4 o = make_float4(acc[i][0], acc[i][1], acc[i][2], acc[i][3]);
        *(float4*)&C[(size_t)(m0 + (ty << 2) + i) * 512 + n0 + (tx << 2)] = o;
    }
}

// ---------------- pointwise ----------------
__global__ void diffk(const float* __restrict__ s, const float* __restrict__ t,
                      float* __restrict__ d) {
    int n4 = NTOT / 4;
    for (int i = blockIdx.x * blockDim.x + threadIdx.x; i < n4; i += gridDim.x * blockDim.x) {
        float4 sv = ((const float4*)s)[i], tv = ((const float4*)t)[i];
        ((float4*)d)[i] = make_float4(sv.x - tv.x, sv.y - tv.y, sv.z - tv.z, sv.w - tv.w);
    }
}

__global__ void maskmul(const float* __restrict__ m, float* __restrict__ gx,
                        float* __restrict__ gy) {
    int n4 = NTOT / 4;
    for (int i = blockIdx.x * blockDim.x + threadIdx.x; i < n4; i += gridDim.x * blockDim.x) {
        float4 mv = ((const float4*)m)[i];
        float4 xv = ((float4*)gx)[i];
        float4 yv = ((float4*)gy)[i];
        ((float4*)gx)[i] = make_float4(xv.x * mv.x, xv.y * mv.y, xv.z * mv.z, xv.w * mv.w);
        ((float4*)gy)[i] = make_float4(yv.x * mv.x, yv.y * mv.y, yv.z * mv.z, yv.w * mv.w);
    }
}

__global__ void napply(const float* __restrict__ Gx, const float* __restrict__ Gy,
                       float* __restrict__ np) {
    for (int idx = blockIdx.x * blockDim.x + threadIdx.x; idx < NTOT; idx += gridDim.x * blockDim.x) {
        int r = idx & (CH - 1);
        int u = r >> 9, v = r & 511;
        float num = kPiOver512 * ((float)v * Gx[idx] + (float)u * Gy[idx]);
        float den = 1e-10f - kPi2Norm * (float)(u * u + v * v);
        float eps = (u ? 2.0f : 1.0f) * (v ? 2.0f : 1.0f) * kInvHW;
        np[idx] = eps * num / den;
    }
}

// ---------------- reductions (deterministic two-stage) ----------------
// scal layout (floats): [0..191] partT, [192..287] partI, [288..383] partU, [384..389] shift[z]
__global__ __launch_bounds__(256) void red_tm(const float* __restrict__ t,
                                              const float* __restrict__ m,
                                              float* __restrict__ scal) {
    int bid = blockIdx.x;             // 0..191
    int z = bid >> 5, seg = bid & 31;
    int tid = threadIdx.x;
    const float4* tz = (const float4*)(t + (size_t)z * CH + seg * 8192);
    const float4* mz = (const float4*)(m + (size_t)z * CH + seg * 8192);
    float st = 0.f, si = 0.f;
    for (int i = tid; i < 2048; i += 256) {
        float4 tv = tz[i];
        st += (tv.x + tv.y) + (tv.z + tv.w);
        if (z < 3) {
            float4 mv = mz[i];
            si += 4.0f - ((mv.x + mv.y) + (mv.z + mv.w));
        }
    }
    __shared__ float rT[256], rI[256];
    rT[tid] = st; rI[tid] = si;
    __syncthreads();
    for (int s2 = 128; s2 > 0; s2 >>= 1) {
        if (tid < s2) { rT[tid] += rT[tid + s2]; rI[tid] += rI[tid + s2]; }
        __syncthreads();
    }
    if (tid == 0) {
        scal[z * 32 + seg] = rT[0];
        if (z < 3) scal[192 + z * 32 + seg] = rI[0];
    }
}

__global__ __launch_bounds__(256) void red_u(const float* __restrict__ u,
                                             const float* __restrict__ m,
                                             float* __restrict__ scal) {
    int bid = blockIdx.x;             // 0..95
    int c = bid >> 5, seg = bid & 31;
    int tid = threadIdx.x;
    const float4* uz = (const float4*)(u + (size_t)c * CH + seg * 8192);
    const float4* mz = (const float4*)(m + (size_t)c * CH + seg * 8192);
    float su = 0.f;
    for (int i = tid; i < 2048; i += 256) {
        float4 uv = uz[i];
        float4 mv = mz[i];
        su += uv.x * (1.f - mv.x) + uv.y * (1.f - mv.y)
            + uv.z * (1.f - mv.z) + uv.w * (1.f - mv.w);
    }
    __shared__ float r[256];
    r[tid] = su;
    __syncthreads();
    for (int s2 = 128; s2 > 0; s2 >>= 1) {
        if (tid < s2) r[tid] += r[tid + s2];
        __syncthreads();
    }
    if (tid == 0) scal[288 + c * 32 + seg] = r[0];
}

__global__ void red_final(float* __restrict__ scal) {
    __shared__ float mt[6], wmu[3];
    int tid = threadIdx.x;
    if (tid < 6) {
        float s = 0.f;
        for (int k = 0; k < 32; ++k) s += scal[tid * 32 + k];
        mt[tid] = s * (1.0f / (float)CH);
    }
    if (tid >= 8 && tid < 11) {
        int c = tid - 8;
        float si = 0.f, su = 0.f;
        for (int k = 0; k < 32; ++k) { si += scal[192 + c * 32 + k]; su += scal[288 + c * 32 + k]; }
        wmu[c] = su / si;
    }
    __syncthreads();
    if (tid < 6) {
        int c = tid % 3;
        scal[384 + tid] = -mt[tid] + mt[c] - wmu[c];
    }
}

__global__ void final_out(const float* __restrict__ t, const float* __restrict__ u,
                          const float* __restrict__ scal, float* __restrict__ out) {
    int n4 = NTOT / 4;
    for (int i = blockIdx.x * blockDim.x + threadIdx.x; i < n4; i += gridDim.x * blockDim.x) {
        int z = i >> 16;                 // CH/4 = 65536
        float sh = scal[384 + z];
        float4 tv = ((const float4*)t)[i];
        float4 uv = ((const float4*)u)[i];
        ((float4*)out)[i] = make_float4(tv.x + uv.x + sh, tv.y + uv.y + sh,
                                        tv.z + uv.z + sh, tv.w + uv.w + sh);
    }
}

extern "C" void kernel_launch(void* const* d_in, const int* in_sizes, int n_in,
                              void* d_out, int out_size, void* d_ws, size_t ws_size,
                              hipStream_t stream) {
    const float* t = (const float*)d_in[0];
    const float* s = (const float*)d_in[1];
    const float* m = (const float*)d_in[2];
    float* out = (float*)d_out;
    float* F = (float*)d_ws;

    const int S = CH;
    if (ws_size < (size_t)(31 * CH + 64) * sizeof(float)) return;

    float* Mc  = F + 0 * S;
    float* Ms  = F + 1 * S;
    float* McT = F + 2 * S;
    float* MsT = F + 3 * S;
    float* Msw = F + 4 * S;   // reused as scalar area once G is built
    float* G   = F + 5 * S;
    float* GT  = F + 6 * S;
    float* B0  = F + 7  * S;  // [6][CH]
    float* B1  = F + 13 * S;
    float* B2  = F + 19 * S;
    float* B3  = F + 25 * S;
    float* scal = Msw;

    build_tables<<<1024, 256, 0, stream>>>(Mc, Ms, McT, MsT, Msw);

    // G = Mc^T * Msw ; GT = G^T
    gemm_dual<<<dim3(8, 8, 1), 256, 0, stream>>>(McT, 0, Msw, 0, G, 0,
                                                 McT, 0, Msw, 0, G, 0, 1);
    transpose512<<<dim3(16, 16), 256, 0, stream>>>(G, GT);

    // d = s - t  -> B1
    diffk<<<1536, 256, 0, stream>>>(s, t, B1);

    // stage-1 sums of t and inv-mask (Msw free now)
    red_tm<<<192, 256, 0, stream>>>(t, m, scal);

    // L1: gxd = d*G -> B0 ; gyd = G^T*d -> B2
    gemm_dual<<<dim3(8, 8, 12), 256, 0, stream>>>(B1, S, G, 0, B0, S,
                                                  GT, 0, B1, S, B2, S, 6);

    // mask multiply (in place)
    maskmul<<<1536, 256, 0, stream>>>(m, B0, B2);

    // L2: P = Mc*ux -> B1 ; Q = Ms*uy -> B3
    gemm_dual<<<dim3(8, 8, 12), 256, 0, stream>>>(Mc, 0, B0, S, B1, S,
                                                  Ms, 0, B2, S, B3, S, 6);

    // L3: Gx = P*Ms^T -> B0 ; Gy = Q*Mc^T -> B2
    gemm_dual<<<dim3(8, 8, 12), 256, 0, stream>>>(B1, S, MsT, 0, B0, S,
                                                  B3, S, McT, 0, B2, S, 6);

    // n' -> B1
    napply<<<2048, 256, 0, stream>>>(B0, B2, B1);

    // L4: R = Mc^T * n' -> B3
    gemm_dual<<<dim3(8, 8, 6), 256, 0, stream>>>(McT, 0, B1, S, B3, S,
                                                 McT, 0, B1, S, B3, S, 6);
    // L5: u = R * Mc -> B0
    gemm_dual<<<dim3(8, 8, 6), 256, 0, stream>>>(B3, S, Mc, 0, B0, S,
                                                 B3, S, Mc, 0, B0, S, 6);

    // stage-1 sums of u*inv ; combine ; output
    red_u<<<96, 256, 0, stream>>>(B0, m, scal);
    red_final<<<1, 64, 0, stream>>>(scal);
    final_out<<<1536, 256, 0, stream>>>(t, B0, scal, out);
}

// Round 3
// 155.786 us; speedup vs baseline: 3.0399x; 2.3885x over previous
//
#include <hip/hip_runtime.h>

// Poisson composition via real DCT/DST algebra, GEMMs on matrix cores using
// split-bf16 (hi/lo) 3-MFMA products with fp32 accumulation.
//
// All GEMMs in TN form: C[m][n] = sum_k A[m][k] * Bt[n][k], A/Bt bf16 hi+lo.
// Chain: d = s-t; gx = d*G, gyT = dT*G (Bt=G^T); ux^T,m*gy -> L2 with Bt=Mc;
// L3 -> Gx,Gy spectra; napply pointwise; L4/L5 inverse DCT; mean matching.

#define CH 262144   // 512*512
#define NCH 6
#define NTOT (NCH*CH)

typedef short bf16x8 __attribute__((ext_vector_type(8)));
typedef float f32x4  __attribute__((ext_vector_type(4)));

static constexpr float kPi        = 3.14159265358979323846f;
static constexpr float kPiOver512 = 0.006135923151542565f;   // pi/512
static constexpr float kPi2Norm   = 3.7649933338155804e-05f; // pi^2/512^2
static constexpr float kInvHW     = 3.814697265625e-06f;     // 1/512^2

__device__ __forceinline__ unsigned short f2bf(float x) {
    unsigned u = __float_as_uint(x);
    u += 0x7fffu + ((u >> 16) & 1u);
    return (unsigned short)(u >> 16);
}
__device__ __forceinline__ float bf2f(unsigned short h) {
    return __uint_as_float(((unsigned)h) << 16);
}
__device__ __forceinline__ void split_store(float v, short* ph, short* pl) {
    unsigned short h = f2bf(v);
    *ph = (short)h;
    *pl = (short)f2bf(v - bf2f(h));
}

// ---------------- tables (bf16 hi/lo, all coalesced writes) ----------------
__global__ void build_tables_bf(short* Mc_h, short* Mc_l, short* Ms_h, short* Ms_l,
                                short* McT_h, short* McT_l, short* MswT_h, short* MswT_l) {
    int idx = blockIdx.x * blockDim.x + threadIdx.x;
    if (idx >= CH) return;
    int a = idx >> 9, b = idx & 511;
    // Mc[u=a][i=b], Ms[u=a][i=b]
    int p1 = (a * (2 * b + 1)) & 2047;
    float s1, c1; sincosf((float)p1 * (kPi / 1024.0f), &s1, &c1);
    split_store(c1, Mc_h + idx, Mc_l + idx);
    split_store(s1, Ms_h + idx, Ms_l + idx);
    // McT[i=a][u=b] = cos(pi*b*(2a+1)/1024); MswT[j=a][v=b] = -(2pi b/512^2) sin(...)
    int p2 = (b * (2 * a + 1)) & 2047;
    float s2, c2; sincosf((float)p2 * (kPi / 1024.0f), &s2, &c2);
    split_store(c2, McT_h + idx, McT_l + idx);
    split_store((-2.0f * kPi * (float)b * kInvHW) * s2, MswT_h + idx, MswT_l + idx);
}

// ---------------- split-bf16 MFMA GEMM (TN), dual-op, 64x64 tiles ----------------
__device__ __forceinline__ void gl_lds16(const short* g, short* l) {
    __builtin_amdgcn_global_load_lds(
        (const __attribute__((address_space(1))) void*)g,
        (__attribute__((address_space(3))) void*)l, 16, 0, 0);
}

__global__ __launch_bounds__(256) void gemm_tn(
    const short* Ah0, const short* Al0, int sA0,
    const short* Bh0, const short* Bl0, int sB0,
    float* C0, int sC0,
    const short* Ah1, const short* Al1, int sA1,
    const short* Bh1, const short* Bl1, int sB1,
    float* C1, int sC1, int zsplit)
{
    __shared__ short LAh[2048], LAl[2048], LBh[2048], LBl[2048];
    int z = blockIdx.z;
    const short *Ah, *Al, *Bh, *Bl; float* C;
    if (z < zsplit) {
        Ah = Ah0 + (size_t)z * sA0; Al = Al0 + (size_t)z * sA0;
        Bh = Bh0 + (size_t)z * sB0; Bl = Bl0 + (size_t)z * sB0;
        C  = C0  + (size_t)z * sC0;
    } else {
        int zz = z - zsplit;
        Ah = Ah1 + (size_t)zz * sA1; Al = Al1 + (size_t)zz * sA1;
        Bh = Bh1 + (size_t)zz * sB1; Bl = Bl1 + (size_t)zz * sB1;
        C  = C1  + (size_t)zz * sC1;
    }
    int tid = threadIdx.x;
    int l = tid & 63, w = tid >> 6;
    int wr = w >> 1, wc = w & 1;
    int m0 = blockIdx.y * 64, n0 = blockIdx.x * 64;

    // staging: wave w covers 16B-granules [w*64, w*64+64) of each 64x32 tile.
    // physical granule p = w*64 + l -> row = p>>2, kc_phys = p&3,
    // logical kchunk = kc_phys ^ (row&3)  (XOR swizzle, bijective per row)
    int srow = w * 16 + (l >> 2);
    int skc  = (l & 3) ^ ((l >> 2) & 3);
    const short* gA_h = Ah + (size_t)(m0 + srow) * 512 + 8 * skc;
    const short* gA_l = Al + (size_t)(m0 + srow) * 512 + 8 * skc;
    const short* gB_h = Bh + (size_t)(n0 + srow) * 512 + 8 * skc;
    const short* gB_l = Bl + (size_t)(n0 + srow) * 512 + 8 * skc;
    short* dAh = LAh + w * 512;   // wave-uniform dest (HW scatters lane*16B)
    short* dAl = LAl + w * 512;
    short* dBh = LBh + w * 512;
    short* dBl = LBl + w * 512;

    // fragment reads: row = tile row, kchunk = l>>4, swizzled by row&3 (= l&3)
    int kx = 8 * ((l >> 4) ^ (l & 3));
    int offA = (wr * 32 + (l & 15)) * 32 + kx;   // + q*512 per 16-row group
    int offB = (wc * 32 + (l & 15)) * 32 + kx;   // + p*512

    f32x4 acc[2][2];
#pragma unroll
    for (int q = 0; q < 2; ++q)
#pragma unroll
        for (int p = 0; p < 2; ++p)
            acc[q][p] = (f32x4){0.f, 0.f, 0.f, 0.f};

    for (int k0 = 0; k0 < 512; k0 += 32) {
        gl_lds16(gA_h + k0, dAh);
        gl_lds16(gA_l + k0, dAl);
        gl_lds16(gB_h + k0, dBh);
        gl_lds16(gB_l + k0, dBl);
        __syncthreads();
        bf16x8 ah[2], al[2], bh[2], bl[2];
#pragma unroll
        for (int q = 0; q < 2; ++q) {
            ah[q] = *(const bf16x8*)&LAh[offA + q * 512];
            al[q] = *(const bf16x8*)&LAl[offA + q * 512];
        }
#pragma unroll
        for (int p = 0; p < 2; ++p) {
            bh[p] = *(const bf16x8*)&LBh[offB + p * 512];
            bl[p] = *(const bf16x8*)&LBl[offB + p * 512];
        }
#pragma unroll
        for (int q = 0; q < 2; ++q)
#pragma unroll
            for (int p = 0; p < 2; ++p) {
                acc[q][p] = __builtin_amdgcn_mfma_f32_16x16x32_bf16(ah[q], bh[p], acc[q][p], 0, 0, 0);
                acc[q][p] = __builtin_amdgcn_mfma_f32_16x16x32_bf16(ah[q], bl[p], acc[q][p], 0, 0, 0);
                acc[q][p] = __builtin_amdgcn_mfma_f32_16x16x32_bf16(al[q], bh[p], acc[q][p], 0, 0, 0);
            }
        __syncthreads();
    }

    int crow = m0 + wr * 32 + (l >> 4) * 4;
    int ccol = n0 + wc * 32 + (l & 15);
#pragma unroll
    for (int q = 0; q < 2; ++q)
#pragma unroll
        for (int p = 0; p < 2; ++p)
#pragma unroll
            for (int rr = 0; rr < 4; ++rr)
                C[(size_t)(crow + q * 16 + rr) * 512 + ccol + p * 16] = acc[q][p][rr];
}

// ---------------- pointwise / split passes ----------------
// generic transpose + split: out[j][i] = split(in[i][j])
__global__ void tsplit(const float* __restrict__ in, int sIn,
                       short* __restrict__ oh, short* __restrict__ ol, int sO) {
    __shared__ float tile[32][33];
    int z = blockIdx.z;
    in += (size_t)z * sIn; oh += (size_t)z * sO; ol += (size_t)z * sO;
    int bx = blockIdx.x * 32, by = blockIdx.y * 32;
    int tx = threadIdx.x & 31, ty = threadIdx.x >> 5;
    for (int r = ty; r < 32; r += 8) tile[r][tx] = in[(by + r) * 512 + bx + tx];
    __syncthreads();
    for (int r = ty; r < 32; r += 8) {
        int o = (bx + r) * 512 + by + tx;
        split_store(tile[tx][r], oh + o, ol + o);
    }
}

// natural split (no transpose), full range
__global__ void nsplit(const float* __restrict__ in, short* __restrict__ oh,
                       short* __restrict__ ol) {
    for (int i = blockIdx.x * blockDim.x + threadIdx.x; i < NTOT; i += gridDim.x * blockDim.x)
        split_store(in[i], oh + i, ol + i);
}

// d = s - t: natural split -> (nh,nl), transposed split -> (th,tl)
__global__ void diff_split(const float* __restrict__ s, const float* __restrict__ t,
                           short* __restrict__ nh, short* __restrict__ nl,
                           short* __restrict__ th, short* __restrict__ tl) {
    __shared__ float tile[32][33];
    int z = blockIdx.z;
    s += (size_t)z * CH; t += (size_t)z * CH;
    nh += (size_t)z * CH; nl += (size_t)z * CH;
    th += (size_t)z * CH; tl += (size_t)z * CH;
    int bx = blockIdx.x * 32, by = blockIdx.y * 32;
    int tx = threadIdx.x & 31, ty = threadIdx.x >> 5;
    for (int r = ty; r < 32; r += 8) {
        int idx = (by + r) * 512 + bx + tx;
        float v = s[idx] - t[idx];
        tile[r][tx] = v;
        split_store(v, nh + idx, nl + idx);
    }
    __syncthreads();
    for (int r = ty; r < 32; r += 8) {
        int o = (bx + r) * 512 + by + tx;
        split_store(tile[tx][r], th + o, tl + o);
    }
}

// uxT[j][i] = m[i][j]*gx[i][j]; uy[i][j] = m[i][j]*gyT[j][i]
__global__ void mask_split(const float* __restrict__ gx, const float* __restrict__ gyT,
                           const float* __restrict__ m,
                           short* __restrict__ xh, short* __restrict__ xl,
                           short* __restrict__ yh, short* __restrict__ yl) {
    __shared__ float ta[32][33], tb[32][33];
    int z = blockIdx.z;
    gx += (size_t)z * CH; gyT += (size_t)z * CH; m += (size_t)z * CH;
    xh += (size_t)z * CH; xl += (size_t)z * CH;
    yh += (size_t)z * CH; yl += (size_t)z * CH;
    int bx = blockIdx.x * 32, by = blockIdx.y * 32;
    int tx = threadIdx.x & 31, ty = threadIdx.x >> 5;
    for (int r = ty; r < 32; r += 8) {
        int idx = (by + r) * 512 + bx + tx;
        ta[r][tx] = m[idx] * gx[idx];
        tb[r][tx] = gyT[(bx + r) * 512 + by + tx];
    }
    __syncthreads();
    for (int r = ty; r < 32; r += 8) {
        int ot = (bx + r) * 512 + by + tx;         // transposed index
        split_store(ta[tx][r], xh + ot, xl + ot);
        int on = (by + r) * 512 + bx + tx;         // natural index
        split_store(m[on] * tb[tx][r], yh + on, yl + on);
    }
}

// n'[u][v] pointwise from Gx,Gy then transposed split -> npT[v][u]
__global__ void napply_tsplit(const float* __restrict__ Gx, const float* __restrict__ Gy,
                              short* __restrict__ oh, short* __restrict__ ol) {
    __shared__ float tile[32][33];
    int z = blockIdx.z;
    Gx += (size_t)z * CH; Gy += (size_t)z * CH;
    oh += (size_t)z * CH; ol += (size_t)z * CH;
    int bx = blockIdx.x * 32, by = blockIdx.y * 32;
    int tx = threadIdx.x & 31, ty = threadIdx.x >> 5;
    for (int r = ty; r < 32; r += 8) {
        int u = by + r, v = bx + tx;
        int idx = u * 512 + v;
        float num = kPiOver512 * ((float)v * Gx[idx] + (float)u * Gy[idx]);
        float den = 1e-10f - kPi2Norm * (float)(u * u + v * v);
        float eps = (u ? 2.0f : 1.0f) * (v ? 2.0f : 1.0f) * kInvHW;
        tile[r][tx] = eps * num / den;
    }
    __syncthreads();
    for (int r = ty; r < 32; r += 8) {
        int o = (bx + r) * 512 + by + tx;
        split_store(tile[tx][r], oh + o, ol + o);
    }
}

// ---------------- reductions (deterministic two-stage) ----------------
__global__ __launch_bounds__(256) void red_tm(const float* __restrict__ t,
                                              const float* __restrict__ m,
                                              float* __restrict__ scal) {
    int bid = blockIdx.x;             // 0..191
    int z = bid >> 5, seg = bid & 31;
    int tid = threadIdx.x;
    const float4* tz = (const float4*)(t + (size_t)z * CH + seg * 8192);
    const float4* mz = (const float4*)(m + (size_t)z * CH + seg * 8192);
    float st = 0.f, si = 0.f;
    for (int i = tid; i < 2048; i += 256) {
        float4 tv = tz[i];
        st += (tv.x + tv.y) + (tv.z + tv.w);
        if (z < 3) {
            float4 mv = mz[i];
            si += 4.0f - ((mv.x + mv.y) + (mv.z + mv.w));
        }
    }
    __shared__ float rT[256], rI[256];
    rT[tid] = st; rI[tid] = si;
    __syncthreads();
    for (int s2 = 128; s2 > 0; s2 >>= 1) {
        if (tid < s2) { rT[tid] += rT[tid + s2]; rI[tid] += rI[tid + s2]; }
        __syncthreads();
    }
    if (tid == 0) {
        scal[z * 32 + seg] = rT[0];
        if (z < 3) scal[192 + z * 32 + seg] = rI[0];
    }
}

__global__ __launch_bounds__(256) void red_u(const float* __restrict__ u,
                                             const float* __restrict__ m,
                                             float* __restrict__ scal) {
    int bid = blockIdx.x;             // 0..95
    int c = bid >> 5, seg = bid & 31;
    int tid = threadIdx.x;
    const float4* uz = (const float4*)(u + (size_t)c * CH + seg * 8192);
    const float4* mz = (const float4*)(m + (size_t)c * CH + seg * 8192);
    float su = 0.f;
    for (int i = tid; i < 2048; i += 256) {
        float4 uv = uz[i];
        float4 mv = mz[i];
        su += uv.x * (1.f - mv.x) + uv.y * (1.f - mv.y)
            + uv.z * (1.f - mv.z) + uv.w * (1.f - mv.w);
    }
    __shared__ float r[256];
    r[tid] = su;
    __syncthreads();
    for (int s2 = 128; s2 > 0; s2 >>= 1) {
        if (tid < s2) r[tid] += r[tid + s2];
        __syncthreads();
    }
    if (tid == 0) scal[288 + c * 32 + seg] = r[0];
}

__global__ void red_final(float* __restrict__ scal) {
    __shared__ float mt[6], wmu[3];
    int tid = threadIdx.x;
    if (tid < 6) {
        float s = 0.f;
        for (int k = 0; k < 32; ++k) s += scal[tid * 32 + k];
        mt[tid] = s * (1.0f / (float)CH);
    }
    if (tid >= 8 && tid < 11) {
        int c = tid - 8;
        float si = 0.f, su = 0.f;
        for (int k = 0; k < 32; ++k) { si += scal[192 + c * 32 + k]; su += scal[288 + c * 32 + k]; }
        wmu[c] = su / si;
    }
    __syncthreads();
    if (tid < 6) {
        int c = tid % 3;
        scal[384 + tid] = -mt[tid] + mt[c] - wmu[c];
    }
}

__global__ void final_out(const float* __restrict__ t, const float* __restrict__ u,
                          const float* __restrict__ scal, float* __restrict__ out) {
    int n4 = NTOT / 4;
    for (int i = blockIdx.x * blockDim.x + threadIdx.x; i < n4; i += gridDim.x * blockDim.x) {
        int z = i >> 16;                 // CH/4 = 65536
        float sh = scal[384 + z];
        float4 tv = ((const float4*)t)[i];
        float4 uv = ((const float4*)u)[i];
        ((float4*)out)[i] = make_float4(tv.x + uv.x + sh, tv.y + uv.y + sh,
                                        tv.z + uv.z + sh, tv.w + uv.w + sh);
    }
}

extern "C" void kernel_launch(void* const* d_in, const int* in_sizes, int n_in,
                              void* d_out, int out_size, void* d_ws, size_t ws_size,
                              hipStream_t stream) {
    const float* t = (const float*)d_in[0];
    const float* s = (const float*)d_in[1];
    const float* m = (const float*)d_in[2];
    float* out = (float*)d_out;
    float* F = (float*)d_ws;
    if (ws_size < (size_t)(31 * CH + 64) * sizeof(float)) return;

    float* F0   = F;                        // 6 CH fp32
    float* F1   = F + 6 * (size_t)CH;       // 6 CH fp32
    float* Gf32 = F + 12 * (size_t)CH;      // 1 CH fp32 (later reused as scal)
    float* scal = Gf32;
    short* T = (short*)(F + 13 * (size_t)CH);
    short *Mc_h = T,            *Mc_l = T + CH,
          *Ms_h = T + 2 * CH,   *Ms_l = T + 3 * CH,
          *McT_h = T + 4 * CH,  *McT_l = T + 5 * CH,
          *MswT_h = T + 6 * CH, *MswT_l = T + 7 * CH,
          *GT_h = T + 8 * CH,   *GT_l = T + 9 * CH;
    short* SA = (short*)(F + 18 * (size_t)CH);   // bankA: hi [6CH], lo [6CH]
    short* SB = (short*)(F + 24 * (size_t)CH);   // bankB
    short* SAl = SA + 6 * (size_t)CH;
    short* SBl = SB + 6 * (size_t)CH;

    build_tables_bf<<<1024, 256, 0, stream>>>(Mc_h, Mc_l, Ms_h, Ms_l,
                                              McT_h, McT_l, MswT_h, MswT_l);

    // G = McT x MswT^T -> Gf32 ; split-transpose -> GT (Bt role for L1)
    gemm_tn<<<dim3(8, 8, 1), 256, 0, stream>>>(McT_h, McT_l, 0, MswT_h, MswT_l, 0, Gf32, 0,
                                               McT_h, McT_l, 0, MswT_h, MswT_l, 0, Gf32, 0, 1);
    tsplit<<<dim3(16, 16, 1), 256, 0, stream>>>(Gf32, 0, GT_h, GT_l, 0);

    // d = s - t: natural -> bankA, transposed -> bankB
    diff_split<<<dim3(16, 16, 6), 256, 0, stream>>>(s, t, SA, SAl, SB, SBl);

    // stage-1 sums of t and inv-mask (Gf32 free now)
    red_tm<<<192, 256, 0, stream>>>(t, m, scal);

    // L1: gx = d*G -> F0 ; gyT = dT*G -> F1
    gemm_tn<<<dim3(8, 8, 12), 256, 0, stream>>>(SA, SAl, CH, GT_h, GT_l, 0, F0, CH,
                                                SB, SBl, CH, GT_h, GT_l, 0, F1, CH, 6);

    // mask: uxT -> bankA, uy -> bankB
    mask_split<<<dim3(16, 16, 6), 256, 0, stream>>>(F0, F1, m, SA, SAl, SB, SBl);

    // L2: PT = uxT*Mc^T(Bt=Mc) -> F0 ; W = uy*Mc^T(Bt=Mc) -> F1
    gemm_tn<<<dim3(8, 8, 12), 256, 0, stream>>>(SA, SAl, CH, Mc_h, Mc_l, 0, F0, CH,
                                                SB, SBl, CH, Mc_h, Mc_l, 0, F1, CH, 6);

    // split: P_b = PT^T -> bankA ; WT_b = W^T -> bankB
    tsplit<<<dim3(16, 16, 6), 256, 0, stream>>>(F0, CH, SA, SAl, CH);
    tsplit<<<dim3(16, 16, 6), 256, 0, stream>>>(F1, CH, SB, SBl, CH);

    // L3: Gx = P*Ms^T -> F0 ; Gy = Ms*WT^T -> F1
    gemm_tn<<<dim3(8, 8, 12), 256, 0, stream>>>(SA, SAl, CH, Ms_h, Ms_l, 0, F0, CH,
                                                Ms_h, Ms_l, 0, SB, SBl, CH, F1, CH, 6);

    // n' pointwise, transposed split -> bankA (npT[v][u])
    napply_tsplit<<<dim3(16, 16, 6), 256, 0, stream>>>(F0, F1, SA, SAl);

    // L4: R = McT * npT^T -> F0
    gemm_tn<<<dim3(8, 8, 6), 256, 0, stream>>>(McT_h, McT_l, 0, SA, SAl, CH, F0, CH,
                                               McT_h, McT_l, 0, SA, SAl, CH, F0, CH, 6);

    // natural split R -> bankB
    nsplit<<<1536, 256, 0, stream>>>(F0, SB, SBl);

    // L5: U = R * Mc (Bt=McT) -> F1
    gemm_tn<<<dim3(8, 8, 6), 256, 0, stream>>>(SB, SBl, CH, McT_h, McT_l, 0, F1, CH,
                                               SB, SBl, CH, McT_h, McT_l, 0, F1, CH, 6);

    // mean matching + output
    red_u<<<96, 256, 0, stream>>>(F1, m, scal);
    red_final<<<1, 64, 0, stream>>>(scal);
    final_out<<<1536, 256, 0, stream>>>(t, F1, scal, out);
}

// Round 4
// 124.256 us; speedup vs baseline: 3.8113x; 1.2537x over previous
//
#include <hip/hip_runtime.h>

// Poisson composition via real DCT/DST algebra on matrix cores (split-bf16,
// 3-MFMA). 11 launches. G computed in closed form:
//   G[i][j] = (pi/1024)*(h(i+j+1) + h(j-i)),  h(k) = (-1)^k * cot(pi*k/1024).
// Chain (TN GEMMs, C[m][n] = sum_k A[m][k]*Bt[n][k]):
//   d=s-t (nat+T split) -> L1: gx=d*G, gyT=dT*G -> mask -> uxT,uyT
//   L2: P=Mc*ux, Q=Ms*uy -> psplit -> L3: GxT=Ms~P, GyT=Mc~Q
//   napply (pointwise, transposed layout) -> npT -> L4: R=McT~npT (split out)
//   L5: U=R~McT (+fused masked-dot partials) -> final_out (t+U+shift).

#define CH 262144   // 512*512
#define NCH 6
#define NTOT (NCH*CH)

typedef short bf16x8 __attribute__((ext_vector_type(8)));
typedef float f32x4  __attribute__((ext_vector_type(4)));

static constexpr float kPi        = 3.14159265358979323846f;
static constexpr float kPiOver512 = 0.006135923151542565f;   // pi/512
static constexpr float kPi2Norm   = 3.7649933338155804e-05f; // pi^2/512^2
static constexpr float kInvHW     = 3.814697265625e-06f;     // 1/512^2

__device__ __forceinline__ unsigned short f2bf(float x) {
    unsigned u = __float_as_uint(x);
    u += 0x7fffu + ((u >> 16) & 1u);
    return (unsigned short)(u >> 16);
}
__device__ __forceinline__ float bf2f(unsigned short h) {
    return __uint_as_float(((unsigned)h) << 16);
}
__device__ __forceinline__ void split_store(float v, short* ph, short* pl) {
    unsigned short h = f2bf(v);
    *ph = (short)h;
    *pl = (short)f2bf(v - bf2f(h));
}

// ---------------- tables: Mc, Ms, McT, GT (closed form), all hi/lo ----------
__device__ __forceinline__ float hfun(int k) {
    if (k == 0) return 0.f;
    float sgn = 1.f;
    if (k < 0) { k = -k; sgn = -1.f; }
    if (k > 512) { k = 1024 - k; sgn = -sgn; }
    float sv, cv;
    sincosf((float)k * (kPi / 1024.0f), &sv, &cv);
    float v = cv / sv;                     // cot, angle <= pi/2 (accurate)
    if (k & 1) v = -v;
    return sgn * v;
}

__global__ void build_tables(short* Mc_h, short* Mc_l, short* Ms_h, short* Ms_l,
                             short* McT_h, short* McT_l, short* GT_h, short* GT_l) {
    int idx = blockIdx.x * blockDim.x + threadIdx.x;
    if (idx >= CH) return;
    int a = idx >> 9, b = idx & 511;
    int p1 = (a * (2 * b + 1)) & 2047;
    float s1, c1; sincosf((float)p1 * (kPi / 1024.0f), &s1, &c1);
    split_store(c1, Mc_h + idx, Mc_l + idx);
    split_store(s1, Ms_h + idx, Ms_l + idx);
    int p2 = (b * (2 * a + 1)) & 2047;
    float c2 = __cosf(0.f), s2; sincosf((float)p2 * (kPi / 1024.0f), &s2, &c2);
    split_store(c2, McT_h + idx, McT_l + idx);
    // GT[j=a][i=b] = G[b][a]
    float g = (kPi / 1024.0f) * (hfun(a + b + 1) + hfun(a - b));
    split_store(g, GT_h + idx, GT_l + idx);
}

// ---------------- split-bf16 MFMA GEMM (TN), dual-op, 64x64, BK=32 dbuf ----
__device__ __forceinline__ void gl_lds16(const short* g, const short* l) {
    __builtin_amdgcn_global_load_lds(
        (const __attribute__((address_space(1))) void*)g,
        (__attribute__((address_space(3))) void*)l, 16, 0, 0);
}

// OM: 0 = fp32 C out; 1 = split bf16 hi/lo out; 2 = fp32 C out + masked-dot partials
template<int OM>
__global__ __launch_bounds__(256) void gemm_tn(
    const short* __restrict__ Ah0, const short* __restrict__ Al0, int sA0,
    const short* __restrict__ Bh0, const short* __restrict__ Bl0, int sB0,
    float* __restrict__ Cf0, short* __restrict__ Oh0, short* __restrict__ Ol0, int sC0,
    const short* __restrict__ Ah1, const short* __restrict__ Al1, int sA1,
    const short* __restrict__ Bh1, const short* __restrict__ Bl1, int sB1,
    float* __restrict__ Cf1, short* __restrict__ Oh1, short* __restrict__ Ol1, int sC1,
    int zsplit, const float* __restrict__ msk, float* __restrict__ redp)
{
    __shared__ short LS[2][4][2048];   // [buf][Ah,Al,Bh,Bl][64 rows x 32 k]
    int z = blockIdx.z;
    const short *Ah, *Al, *Bh, *Bl; float* Cf; short* Oh; short* Ol; int sC;
    if (z < zsplit) {
        Ah = Ah0 + (size_t)z * sA0; Al = Al0 + (size_t)z * sA0;
        Bh = Bh0 + (size_t)z * sB0; Bl = Bl0 + (size_t)z * sB0;
        Cf = Cf0 ? Cf0 + (size_t)z * sC0 : nullptr;
        Oh = Oh0 ? Oh0 + (size_t)z * sC0 : nullptr;
        Ol = Ol0 ? Ol0 + (size_t)z * sC0 : nullptr;
        sC = sC0;
    } else {
        int zz = z - zsplit;
        Ah = Ah1 + (size_t)zz * sA1; Al = Al1 + (size_t)zz * sA1;
        Bh = Bh1 + (size_t)zz * sB1; Bl = Bl1 + (size_t)zz * sB1;
        Cf = Cf1 ? Cf1 + (size_t)zz * sC1 : nullptr;
        Oh = Oh1 ? Oh1 + (size_t)zz * sC1 : nullptr;
        Ol = Ol1 ? Ol1 + (size_t)zz * sC1 : nullptr;
        sC = sC1;
    }
    (void)sC;
    int tid = threadIdx.x;
    int l = tid & 63, w = tid >> 6;
    int m0 = blockIdx.y * 64, n0 = blockIdx.x * 64;

    // staging: granule p = w*64+l; row = p>>2; phys chunk pc = p&3;
    // logical chunk c = pc ^ s(row), s(r) = (r>>1)&3  (bank-balanced swizzle)
    int p = w * 64 + l;
    int srow = p >> 2;
    int sc = (p & 3) ^ ((srow >> 1) & 3);
    const short* gAh = Ah + (size_t)(m0 + srow) * 512 + 8 * sc;
    const short* gAl = Al + (size_t)(m0 + srow) * 512 + 8 * sc;
    const short* gBh = Bh + (size_t)(n0 + srow) * 512 + 8 * sc;
    const short* gBl = Bl + (size_t)(n0 + srow) * 512 + 8 * sc;

    // fragment read offsets
    int wr = w >> 1, wc = w & 1;
    int lr = l & 15, lc = l >> 4;
    int rA0 = wr * 32 + lr, rA1 = rA0 + 16;
    int rB0 = wc * 32 + lr, rB1 = rB0 + 16;
    int oA0 = rA0 * 32 + 8 * (lc ^ ((rA0 >> 1) & 3));
    int oA1 = rA1 * 32 + 8 * (lc ^ ((rA1 >> 1) & 3));
    int oB0 = rB0 * 32 + 8 * (lc ^ ((rB0 >> 1) & 3));
    int oB1 = rB1 * 32 + 8 * (lc ^ ((rB1 >> 1) & 3));

    f32x4 a00 = {0,0,0,0}, a01 = a00, a10 = a00, a11 = a00;

    // prologue: stage buf0, k0=0
    gl_lds16(gAh, &LS[0][0][w * 512]);
    gl_lds16(gAl, &LS[0][1][w * 512]);
    gl_lds16(gBh, &LS[0][2][w * 512]);
    gl_lds16(gBl, &LS[0][3][w * 512]);
    __syncthreads();

    for (int step = 0; step < 16; ++step) {
        int buf = step & 1;
        if (step < 15) {
            int k0 = (step + 1) * 32;
            int nb = buf ^ 1;
            gl_lds16(gAh + k0, &LS[nb][0][w * 512]);
            gl_lds16(gAl + k0, &LS[nb][1][w * 512]);
            gl_lds16(gBh + k0, &LS[nb][2][w * 512]);
            gl_lds16(gBl + k0, &LS[nb][3][w * 512]);
        }
        bf16x8 ah0 = *(const bf16x8*)&LS[buf][0][oA0];
        bf16x8 ah1 = *(const bf16x8*)&LS[buf][0][oA1];
        bf16x8 al0 = *(const bf16x8*)&LS[buf][1][oA0];
        bf16x8 al1 = *(const bf16x8*)&LS[buf][1][oA1];
        bf16x8 bh0 = *(const bf16x8*)&LS[buf][2][oB0];
        bf16x8 bh1 = *(const bf16x8*)&LS[buf][2][oB1];
        bf16x8 bl0 = *(const bf16x8*)&LS[buf][3][oB0];
        bf16x8 bl1 = *(const bf16x8*)&LS[buf][3][oB1];
        a00 = __builtin_amdgcn_mfma_f32_16x16x32_bf16(ah0, bh0, a00, 0, 0, 0);
        a01 = __builtin_amdgcn_mfma_f32_16x16x32_bf16(ah0, bh1, a01, 0, 0, 0);
        a10 = __builtin_amdgcn_mfma_f32_16x16x32_bf16(ah1, bh0, a10, 0, 0, 0);
        a11 = __builtin_amdgcn_mfma_f32_16x16x32_bf16(ah1, bh1, a11, 0, 0, 0);
        a00 = __builtin_amdgcn_mfma_f32_16x16x32_bf16(ah0, bl0, a00, 0, 0, 0);
        a01 = __builtin_amdgcn_mfma_f32_16x16x32_bf16(ah0, bl1, a01, 0, 0, 0);
        a10 = __builtin_amdgcn_mfma_f32_16x16x32_bf16(ah1, bl0, a10, 0, 0, 0);
        a11 = __builtin_amdgcn_mfma_f32_16x16x32_bf16(ah1, bl1, a11, 0, 0, 0);
        a00 = __builtin_amdgcn_mfma_f32_16x16x32_bf16(al0, bh0, a00, 0, 0, 0);
        a01 = __builtin_amdgcn_mfma_f32_16x16x32_bf16(al0, bh1, a01, 0, 0, 0);
        a10 = __builtin_amdgcn_mfma_f32_16x16x32_bf16(al1, bh0, a10, 0, 0, 0);
        a11 = __builtin_amdgcn_mfma_f32_16x16x32_bf16(al1, bh1, a11, 0, 0, 0);
        __syncthreads();
    }

    int crow = m0 + wr * 32 + lc * 4;
    int ccol = n0 + wc * 32 + lr;
    const f32x4* accs[2][2] = {{&a00, &a01}, {&a10, &a11}};
    float lsum = 0.f;
#pragma unroll
    for (int q = 0; q < 2; ++q)
#pragma unroll
        for (int pp = 0; pp < 2; ++pp)
#pragma unroll
            for (int rr = 0; rr < 4; ++rr) {
                int idx = (crow + q * 16 + rr) * 512 + ccol + pp * 16;
                float v = (*accs[q][pp])[rr];
                if (OM == 1) {
                    split_store(v, Oh + idx, Ol + idx);
                } else {
                    Cf[idx] = v;
                    if (OM == 2)
                        lsum += v * (1.0f - msk[(size_t)z * CH + idx]);
                }
            }
    if (OM == 2) {
        float* red = (float*)LS;
        red[tid] = lsum;
        __syncthreads();
        for (int s2 = 128; s2 > 0; s2 >>= 1) {
            if (tid < s2) red[tid] += red[tid + s2];
            __syncthreads();
        }
        if (tid == 0) redp[z * 64 + blockIdx.y * 8 + blockIdx.x] = red[0];
    }
}

// ---------------- d = s-t: nat + transposed split, fused t/(1-m) partials ----
__global__ __launch_bounds__(256) void diff_split_red(
    const float* __restrict__ s, const float* __restrict__ t, const float* __restrict__ m,
    short* __restrict__ dnh, short* __restrict__ dnl,
    short* __restrict__ dth, short* __restrict__ dtl,
    float* __restrict__ mt, float* __restrict__ mi)
{
    __shared__ float tile[32][33];
    __shared__ float red[512];
    int z = blockIdx.z;
    const float* sz = s + (size_t)z * CH;
    const float* tz = t + (size_t)z * CH;
    const float* mz = m + (size_t)z * CH;
    short* nh = dnh + (size_t)z * CH; short* nl = dnl + (size_t)z * CH;
    short* th = dth + (size_t)z * CH; short* tl = dtl + (size_t)z * CH;
    int bx = blockIdx.x * 32, by = blockIdx.y * 32;
    int tx = threadIdx.x & 31, ty = threadIdx.x >> 5;
    float accT = 0.f, accI = 0.f;
    for (int r = ty; r < 32; r += 8) {
        int idx = (by + r) * 512 + bx + tx;
        float tv = tz[idx];
        float d = sz[idx] - tv;
        tile[r][tx] = d;
        split_store(d, nh + idx, nl + idx);
        accT += tv;
        if (z < 3) accI += 1.0f - mz[idx];
    }
    __syncthreads();
    for (int r = ty; r < 32; r += 8) {
        int o = (bx + r) * 512 + by + tx;
        split_store(tile[tx][r], th + o, tl + o);
    }
    int tid = threadIdx.x;
    red[tid] = accT; red[256 + tid] = accI;
    __syncthreads();
    for (int s2 = 128; s2 > 0; s2 >>= 1) {
        if (tid < s2) { red[tid] += red[tid + s2]; red[256 + tid] += red[256 + tid + s2]; }
        __syncthreads();
    }
    if (tid == 0) {
        int tileid = blockIdx.y * 16 + blockIdx.x;
        mt[z * 256 + tileid] = red[0];
        if (z < 3) mi[z * 256 + tileid] = red[256];
    }
}

// ---------------- mask: uxT = (m.*gx)^T, uyT = gyT .* m^T, split ------------
__global__ __launch_bounds__(256) void mask_split(
    const float* __restrict__ gx, const float* __restrict__ gyT, const float* __restrict__ m,
    short* __restrict__ uxh, short* __restrict__ uxl,
    short* __restrict__ uyh, short* __restrict__ uyl)
{
    __shared__ float pt[32][33], mt_t[32][33];
    int z = blockIdx.z;
    const float* gxz = gx + (size_t)z * CH;
    const float* gyz = gyT + (size_t)z * CH;
    const float* mz = m + (size_t)z * CH;
    short* xh = uxh + (size_t)z * CH; short* xl = uxl + (size_t)z * CH;
    short* yh = uyh + (size_t)z * CH; short* yl = uyl + (size_t)z * CH;
    int I0 = blockIdx.x * 32, J0 = blockIdx.y * 32;
    int tx = threadIdx.x & 31, ty = threadIdx.x >> 5;
    for (int r = ty; r < 32; r += 8) {
        int idx = (I0 + r) * 512 + J0 + tx;
        float mm = mz[idx];
        pt[r][tx] = mm * gxz[idx];
        mt_t[r][tx] = mm;
    }
    __syncthreads();
    for (int r = ty; r < 32; r += 8) {
        int o = (J0 + r) * 512 + I0 + tx;
        split_store(pt[tx][r], xh + o, xl + o);
        split_store(gyz[o] * mt_t[tx][r], yh + o, yl + o);
    }
}

// ---------------- psplit: P,Q fp32 -> bf16 hi/lo (natural) ------------------
__device__ __forceinline__ void split4(float4 v, short4& h, short4& l) {
    split_store(v.x, &h.x, &l.x);
    split_store(v.y, &h.y, &l.y);
    split_store(v.z, &h.z, &l.z);
    split_store(v.w, &h.w, &l.w);
}
__global__ void psplit(const float* __restrict__ P, const float* __restrict__ Q,
                       short* __restrict__ Ph, short* __restrict__ Pl,
                       short* __restrict__ Qh, short* __restrict__ Ql) {
    int n4 = NTOT / 4;
    for (int i = blockIdx.x * blockDim.x + threadIdx.x; i < n4; i += gridDim.x * blockDim.x) {
        short4 h, l;
        split4(((const float4*)P)[i], h, l);
        ((short4*)Ph)[i] = h; ((short4*)Pl)[i] = l;
        split4(((const float4*)Q)[i], h, l);
        ((short4*)Qh)[i] = h; ((short4*)Ql)[i] = l;
    }
}

// ---------------- napply: pointwise on transposed spectra -------------------
// layout [v][u] (row=v=x-freq, col=u=y-freq); np = eps*(pi/512)*(v*Gx+u*Gy)/den
__global__ void napply_split(const float* __restrict__ GxT, const float* __restrict__ GyT,
                             short* __restrict__ oh, short* __restrict__ ol) {
    int n4 = NTOT / 4;
    for (int i = blockIdx.x * blockDim.x + threadIdx.x; i < n4; i += gridDim.x * blockDim.x) {
        int r = (i << 2) & (CH - 1);
        int v = r >> 9, u0 = r & 511;
        float4 gx4 = ((const float4*)GxT)[i];
        float4 gy4 = ((const float4*)GyT)[i];
        float gxa[4] = {gx4.x, gx4.y, gx4.z, gx4.w};
        float gya[4] = {gy4.x, gy4.y, gy4.z, gy4.w};
        short4 h, l;
        short* hp = &h.x; short* lp = &l.x;
        float ev = (v ? 2.0f : 1.0f) * kInvHW;
#pragma unroll
        for (int e = 0; e < 4; ++e) {
            int u = u0 + e;
            float num = kPiOver512 * ((float)v * gxa[e] + (float)u * gya[e]);
            float den = 1e-10f - kPi2Norm * (float)(u * u + v * v);
            float eps = (u ? 2.0f : 1.0f) * ev;
            split_store(eps * num / den, hp + e, lp + e);
        }
        ((short4*)oh)[i] = h;
        ((short4*)ol)[i] = l;
    }
}

// ---------------- final: out = t + U + shift[z] -----------------------------
// part: mt[6*256] @0, mi[3*256] @1536, redU[6*64] @2304
__global__ __launch_bounds__(256) void final_out(
    const float* __restrict__ t, const float* __restrict__ U,
    const float* __restrict__ part, float* __restrict__ out)
{
    __shared__ float mtv[6], wmuv[3];
    int tid = threadIdx.x;
    if (tid < 6) {
        float s2 = 0.f;
        for (int k = 0; k < 256; ++k) s2 += part[tid * 256 + k];
        mtv[tid] = s2 * (1.0f / (float)CH);
    }
    if (tid >= 8 && tid < 11) {
        int c = tid - 8;
        float si = 0.f, su = 0.f;
        for (int k = 0; k < 256; ++k) si += part[1536 + c * 256 + k];
        for (int k = 0; k < 64; ++k) su += part[2304 + c * 64 + k];
        wmuv[c] = su / si;
    }
    __syncthreads();
    int n4 = NTOT / 4;
    for (int i = blockIdx.x * blockDim.x + tid; i < n4; i += gridDim.x * blockDim.x) {
        int z = i >> 16;           // CH/4 = 65536
        int c = z % 3;
        float sh = -mtv[z] + mtv[c] - wmuv[c];
        float4 tv = ((const float4*)t)[i];
        float4 uv = ((const float4*)U)[i];
        ((float4*)out)[i] = make_float4(tv.x + uv.x + sh, tv.y + uv.y + sh,
                                        tv.z + uv.z + sh, tv.w + uv.w + sh);
    }
}

extern "C" void kernel_launch(void* const* d_in, const int* in_sizes, int n_in,
                              void* d_out, int out_size, void* d_ws, size_t ws_size,
                              hipStream_t stream) {
    const float* t = (const float*)d_in[0];
    const float* s = (const float*)d_in[1];
    const float* m = (const float*)d_in[2];
    float* out = (float*)d_out;
    float* F = (float*)d_ws;
    if (ws_size < (size_t)(31 * CH + 64) * sizeof(float)) return;

    float* F0 = F;                       // 6 CH f32
    float* F1 = F + 6 * (size_t)CH;      // 6 CH f32
    short* T  = (short*)(F + 12 * (size_t)CH);   // 8 table arrays (CH shorts each)
    short *Mc_h = T,           *Mc_l = T + (size_t)CH,
          *Ms_h = T + 2*(size_t)CH,  *Ms_l = T + 3*(size_t)CH,
          *McT_h = T + 4*(size_t)CH, *McT_l = T + 5*(size_t)CH,
          *GT_h = T + 6*(size_t)CH,  *GT_l = T + 7*(size_t)CH;
    short* SAh = (short*)(F + 16 * (size_t)CH);  // bank A hi [6CH]
    short* SAl = SAh + 6 * (size_t)CH;           //        lo
    short* SBh = (short*)(F + 22 * (size_t)CH);  // bank B
    short* SBl = SBh + 6 * (size_t)CH;
    float* part = F + 28 * (size_t)CH;           // partials (~2700 floats)

    build_tables<<<1024, 256, 0, stream>>>(Mc_h, Mc_l, Ms_h, Ms_l,
                                           McT_h, McT_l, GT_h, GT_l);

    // d = s-t -> SA (nat), SB (transposed); + t / (1-m) partial sums
    diff_split_red<<<dim3(16, 16, 6), 256, 0, stream>>>(s, t, m, SAh, SAl, SBh, SBl,
                                                        part, part + 1536);

    // L1: gx = d~GT -> F0 ; gyT = dT~GT -> F1
    gemm_tn<0><<<dim3(8, 8, 12), 256, 0, stream>>>(
        SAh, SAl, CH, GT_h, GT_l, 0, F0, nullptr, nullptr, CH,
        SBh, SBl, CH, GT_h, GT_l, 0, F1, nullptr, nullptr, CH, 6, nullptr, nullptr);

    // mask -> uxT (SA), uyT (SB)
    mask_split<<<dim3(16, 16, 6), 256, 0, stream>>>(F0, F1, m, SAh, SAl, SBh, SBl);

    // L2: P = Mc~uxT -> F0 ; Q = Ms~uyT -> F1
    gemm_tn<0><<<dim3(8, 8, 12), 256, 0, stream>>>(
        Mc_h, Mc_l, 0, SAh, SAl, CH, F0, nullptr, nullptr, CH,
        Ms_h, Ms_l, 0, SBh, SBl, CH, F1, nullptr, nullptr, CH, 6, nullptr, nullptr);

    // split P -> SA, Q -> SB
    psplit<<<768, 256, 0, stream>>>(F0, F1, SAh, SAl, SBh, SBl);

    // L3: GxT = Ms~P -> F0 ; GyT = Mc~Q -> F1
    gemm_tn<0><<<dim3(8, 8, 12), 256, 0, stream>>>(
        Ms_h, Ms_l, 0, SAh, SAl, CH, F0, nullptr, nullptr, CH,
        Mc_h, Mc_l, 0, SBh, SBl, CH, F1, nullptr, nullptr, CH, 6, nullptr, nullptr);

    // npT (pointwise) -> SA
    napply_split<<<768, 256, 0, stream>>>(F0, F1, SAh, SAl);

    // L4: R = McT~npT -> SB (split epilogue)
    gemm_tn<1><<<dim3(8, 8, 6), 256, 0, stream>>>(
        McT_h, McT_l, 0, SAh, SAl, CH, nullptr, SBh, SBl, CH,
        McT_h, McT_l, 0, SAh, SAl, CH, nullptr, SBh, SBl, CH, 6, nullptr, nullptr);

    // L5: U = R~McT -> F0, + masked-dot partials
    gemm_tn<2><<<dim3(8, 8, 6), 256, 0, stream>>>(
        SBh, SBl, CH, McT_h, McT_l, 0, F0, nullptr, nullptr, CH,
        SBh, SBl, CH, McT_h, McT_l, 0, F0, nullptr, nullptr, CH, 6, m, part + 2304);

    // out = t + U + shift
    final_out<<<768, 256, 0, stream>>>(t, F0, part, out);
}

// Round 5
// 108.529 us; speedup vs baseline: 4.3636x; 1.1449x over previous
//
#include <hip/hip_runtime.h>

// Poisson composition via real DCT/DST algebra on matrix cores (split-bf16,
// 3-MFMA). 8 launches, all reformat passes fused into GEMM epilogues.
//   G[i][j] = (pi/1024)*(h(i+j+1) + h(j-i)),  h(k) = (-1)^k * cot(pi*k/1024).
// Chain (TN GEMMs, C[m][n] = sum_k A[m][k]*Bt[n][k]):
//   d=s-t (nat->A, T->B) ; L1: gx=d~G, gyT=dT~G, epilogue mask(+T) -> uxT(C), uyT(D)
//   L2: P=Mc~uxT -> A (split), Q=Ms~uyT -> B (split)
//   L3fused: GxT=Ms~P & GyT=Mc~Q in one block, epilogue napply -> npT(C, split)
//   L4: R=McT~npT -> D (split) ; L5: U=R~McT -> F0 (+ masked-dot partials)
//   final_out: out = t + U + shift[z].

#define CH 262144   // 512*512
#define NCH 6
#define NTOT (NCH*CH)

typedef short bf16x8 __attribute__((ext_vector_type(8)));
typedef float f32x4  __attribute__((ext_vector_type(4)));

static constexpr float kPi        = 3.14159265358979323846f;
static constexpr float kPiOver512 = 0.006135923151542565f;   // pi/512
static constexpr float kPi2Norm   = 3.7649933338155804e-05f; // pi^2/512^2
static constexpr float kInvHW     = 3.814697265625e-06f;     // 1/512^2

__device__ __forceinline__ unsigned short f2bf(float x) {
    unsigned u = __float_as_uint(x);
    u += 0x7fffu + ((u >> 16) & 1u);
    return (unsigned short)(u >> 16);
}
__device__ __forceinline__ float bf2f(unsigned short h) {
    return __uint_as_float(((unsigned)h) << 16);
}
__device__ __forceinline__ void split_store(float v, short* ph, short* pl) {
    unsigned short h = f2bf(v);
    *ph = (short)h;
    *pl = (short)f2bf(v - bf2f(h));
}

// ---------------- tables: Mc, Ms, McT, GT (closed form), all hi/lo ----------
__device__ __forceinline__ float hfun(int k) {
    if (k == 0) return 0.f;
    float sgn = 1.f;
    if (k < 0) { k = -k; sgn = -1.f; }
    if (k > 512) { k = 1024 - k; sgn = -sgn; }
    float sv, cv;
    sincosf((float)k * (kPi / 1024.0f), &sv, &cv);
    float v = cv / sv;
    if (k & 1) v = -v;
    return sgn * v;
}

__global__ void build_tables(short* Mc_h, short* Mc_l, short* Ms_h, short* Ms_l,
                             short* McT_h, short* McT_l, short* GT_h, short* GT_l) {
    int idx = blockIdx.x * blockDim.x + threadIdx.x;
    if (idx >= CH) return;
    int a = idx >> 9, b = idx & 511;
    int p1 = (a * (2 * b + 1)) & 2047;
    float s1, c1; sincosf((float)p1 * (kPi / 1024.0f), &s1, &c1);
    split_store(c1, Mc_h + idx, Mc_l + idx);
    split_store(s1, Ms_h + idx, Ms_l + idx);
    int p2 = (b * (2 * a + 1)) & 2047;
    float s2, c2; sincosf((float)p2 * (kPi / 1024.0f), &s2, &c2);
    split_store(c2, McT_h + idx, McT_l + idx);
    float g = (kPi / 1024.0f) * (hfun(a + b + 1) + hfun(a - b));
    split_store(g, GT_h + idx, GT_l + idx);
}

// ---------------- shared GEMM machinery ----------------
__device__ __forceinline__ void gl_lds16(const short* g, const short* l) {
    __builtin_amdgcn_global_load_lds(
        (const __attribute__((address_space(1))) void*)g,
        (__attribute__((address_space(3))) void*)l, 16, 0, 0);
}

// staging swizzle: granule p = w*64+l -> row p>>2, chunk (p&3)^((row>>1)&3)
#define STAGE_IDX(p, srow, sc) int srow = (p) >> 2; int sc = ((p) & 3) ^ ((srow >> 1) & 3);
#define FRAG_OFF(r, lc) ((r) * 32 + 8 * ((lc) ^ (((r) >> 1) & 3)))

// OM: 0 = fp32 C; 1 = split bf16 out; 2 = fp32 C + masked-dot partials
template<int OM>
__global__ __launch_bounds__(256) void gemm_tn(
    const short* __restrict__ Ah0, const short* __restrict__ Al0, int sA0,
    const short* __restrict__ Bh0, const short* __restrict__ Bl0, int sB0,
    float* __restrict__ Cf0, short* __restrict__ Oh0, short* __restrict__ Ol0, int sC0,
    const short* __restrict__ Ah1, const short* __restrict__ Al1, int sA1,
    const short* __restrict__ Bh1, const short* __restrict__ Bl1, int sB1,
    float* __restrict__ Cf1, short* __restrict__ Oh1, short* __restrict__ Ol1, int sC1,
    int zsplit, const float* __restrict__ msk, float* __restrict__ redp)
{
    __shared__ short LS[2][4][2048];
    int z = blockIdx.z;
    const short *Ah, *Al, *Bh, *Bl; float* Cf; short* Oh; short* Ol;
    if (z < zsplit) {
        Ah = Ah0 + (size_t)z * sA0; Al = Al0 + (size_t)z * sA0;
        Bh = Bh0 + (size_t)z * sB0; Bl = Bl0 + (size_t)z * sB0;
        Cf = Cf0 ? Cf0 + (size_t)z * sC0 : nullptr;
        Oh = Oh0 ? Oh0 + (size_t)z * sC0 : nullptr;
        Ol = Ol0 ? Ol0 + (size_t)z * sC0 : nullptr;
    } else {
        int zz = z - zsplit;
        Ah = Ah1 + (size_t)zz * sA1; Al = Al1 + (size_t)zz * sA1;
        Bh = Bh1 + (size_t)zz * sB1; Bl = Bl1 + (size_t)zz * sB1;
        Cf = Cf1 ? Cf1 + (size_t)zz * sC1 : nullptr;
        Oh = Oh1 ? Oh1 + (size_t)zz * sC1 : nullptr;
        Ol = Ol1 ? Ol1 + (size_t)zz * sC1 : nullptr;
    }
    int tid = threadIdx.x;
    int l = tid & 63, w = tid >> 6;
    int m0 = blockIdx.y * 64, n0 = blockIdx.x * 64;

    int p = w * 64 + l;
    STAGE_IDX(p, srow, sc)
    const short* gAh = Ah + (size_t)(m0 + srow) * 512 + 8 * sc;
    const short* gAl = Al + (size_t)(m0 + srow) * 512 + 8 * sc;
    const short* gBh = Bh + (size_t)(n0 + srow) * 512 + 8 * sc;
    const short* gBl = Bl + (size_t)(n0 + srow) * 512 + 8 * sc;

    int wr = w >> 1, wc = w & 1;
    int lr = l & 15, lc = l >> 4;
    int rA0 = wr * 32 + lr, rA1 = rA0 + 16;
    int rB0 = wc * 32 + lr, rB1 = rB0 + 16;
    int oA0 = FRAG_OFF(rA0, lc), oA1 = FRAG_OFF(rA1, lc);
    int oB0 = FRAG_OFF(rB0, lc), oB1 = FRAG_OFF(rB1, lc);

    f32x4 a00 = {0,0,0,0}, a01 = a00, a10 = a00, a11 = a00;

    gl_lds16(gAh, &LS[0][0][w * 512]);
    gl_lds16(gAl, &LS[0][1][w * 512]);
    gl_lds16(gBh, &LS[0][2][w * 512]);
    gl_lds16(gBl, &LS[0][3][w * 512]);
    __syncthreads();

    for (int step = 0; step < 16; ++step) {
        int buf = step & 1;
        if (step < 15) {
            int k0 = (step + 1) * 32;
            int nb = buf ^ 1;
            gl_lds16(gAh + k0, &LS[nb][0][w * 512]);
            gl_lds16(gAl + k0, &LS[nb][1][w * 512]);
            gl_lds16(gBh + k0, &LS[nb][2][w * 512]);
            gl_lds16(gBl + k0, &LS[nb][3][w * 512]);
        }
        bf16x8 ah0 = *(const bf16x8*)&LS[buf][0][oA0];
        bf16x8 ah1 = *(const bf16x8*)&LS[buf][0][oA1];
        bf16x8 al0 = *(const bf16x8*)&LS[buf][1][oA0];
        bf16x8 al1 = *(const bf16x8*)&LS[buf][1][oA1];
        bf16x8 bh0 = *(const bf16x8*)&LS[buf][2][oB0];
        bf16x8 bh1 = *(const bf16x8*)&LS[buf][2][oB1];
        bf16x8 bl0 = *(const bf16x8*)&LS[buf][3][oB0];
        bf16x8 bl1 = *(const bf16x8*)&LS[buf][3][oB1];
        a00 = __builtin_amdgcn_mfma_f32_16x16x32_bf16(ah0, bh0, a00, 0, 0, 0);
        a01 = __builtin_amdgcn_mfma_f32_16x16x32_bf16(ah0, bh1, a01, 0, 0, 0);
        a10 = __builtin_amdgcn_mfma_f32_16x16x32_bf16(ah1, bh0, a10, 0, 0, 0);
        a11 = __builtin_amdgcn_mfma_f32_16x16x32_bf16(ah1, bh1, a11, 0, 0, 0);
        a00 = __builtin_amdgcn_mfma_f32_16x16x32_bf16(ah0, bl0, a00, 0, 0, 0);
        a01 = __builtin_amdgcn_mfma_f32_16x16x32_bf16(ah0, bl1, a01, 0, 0, 0);
        a10 = __builtin_amdgcn_mfma_f32_16x16x32_bf16(ah1, bl0, a10, 0, 0, 0);
        a11 = __builtin_amdgcn_mfma_f32_16x16x32_bf16(ah1, bl1, a11, 0, 0, 0);
        a00 = __builtin_amdgcn_mfma_f32_16x16x32_bf16(al0, bh0, a00, 0, 0, 0);
        a01 = __builtin_amdgcn_mfma_f32_16x16x32_bf16(al0, bh1, a01, 0, 0, 0);
        a10 = __builtin_amdgcn_mfma_f32_16x16x32_bf16(al1, bh0, a10, 0, 0, 0);
        a11 = __builtin_amdgcn_mfma_f32_16x16x32_bf16(al1, bh1, a11, 0, 0, 0);
        __syncthreads();
    }

    int crow = m0 + wr * 32 + lc * 4;
    int ccol = n0 + wc * 32 + lr;
    const f32x4* accs[2][2] = {{&a00, &a01}, {&a10, &a11}};
    float lsum = 0.f;
#pragma unroll
    for (int q = 0; q < 2; ++q)
#pragma unroll
        for (int pp = 0; pp < 2; ++pp)
#pragma unroll
            for (int rr = 0; rr < 4; ++rr) {
                int idx = (crow + q * 16 + rr) * 512 + ccol + pp * 16;
                float v = (*accs[q][pp])[rr];
                if (OM == 1) {
                    split_store(v, Oh + idx, Ol + idx);
                } else {
                    Cf[idx] = v;
                    if (OM == 2)
                        lsum += v * (1.0f - msk[(size_t)z * CH + idx]);
                }
            }
    if (OM == 2) {
        float* red = (float*)LS;
        red[tid] = lsum;
        __syncthreads();
        for (int s2 = 128; s2 > 0; s2 >>= 1) {
            if (tid < s2) red[tid] += red[tid + s2];
            __syncthreads();
        }
        if (tid == 0) redp[z * 64 + blockIdx.y * 8 + blockIdx.x] = red[0];
    }
}

// ---------------- L1 fused: gradients + mask + transpose, split out ---------
__global__ __launch_bounds__(256) void gemm_l1(
    const short* __restrict__ dnh, const short* __restrict__ dnl,
    const short* __restrict__ dth, const short* __restrict__ dtl,
    const short* __restrict__ GTh, const short* __restrict__ GTl,
    const float* __restrict__ msk,
    short* __restrict__ Ch_, short* __restrict__ Cl_,
    short* __restrict__ Dh_, short* __restrict__ Dl_)
{
    __shared__ short LS[2][4][2048];
    int z = blockIdx.z;
    bool gxp = z < 6;
    int zz = gxp ? z : z - 6;
    const short* Ah = (gxp ? dnh : dth) + (size_t)zz * CH;
    const short* Al = (gxp ? dnl : dtl) + (size_t)zz * CH;
    const float* mz = msk + (size_t)zz * CH;

    int tid = threadIdx.x;
    int l = tid & 63, w = tid >> 6;
    int m0 = blockIdx.y * 64, n0 = blockIdx.x * 64;

    int p = w * 64 + l;
    STAGE_IDX(p, srow, sc)
    const short* gAh = Ah + (size_t)(m0 + srow) * 512 + 8 * sc;
    const short* gAl = Al + (size_t)(m0 + srow) * 512 + 8 * sc;
    const short* gBh = GTh + (size_t)(n0 + srow) * 512 + 8 * sc;
    const short* gBl = GTl + (size_t)(n0 + srow) * 512 + 8 * sc;

    int wr = w >> 1, wc = w & 1;
    int lr = l & 15, lc = l >> 4;
    int rA0 = wr * 32 + lr, rA1 = rA0 + 16;
    int rB0 = wc * 32 + lr, rB1 = rB0 + 16;
    int oA0 = FRAG_OFF(rA0, lc), oA1 = FRAG_OFF(rA1, lc);
    int oB0 = FRAG_OFF(rB0, lc), oB1 = FRAG_OFF(rB1, lc);

    f32x4 a00 = {0,0,0,0}, a01 = a00, a10 = a00, a11 = a00;

    gl_lds16(gAh, &LS[0][0][w * 512]);
    gl_lds16(gAl, &LS[0][1][w * 512]);
    gl_lds16(gBh, &LS[0][2][w * 512]);
    gl_lds16(gBl, &LS[0][3][w * 512]);
    __syncthreads();

    for (int step = 0; step < 16; ++step) {
        int buf = step & 1;
        if (step < 15) {
            int k0 = (step + 1) * 32;
            int nb = buf ^ 1;
            gl_lds16(gAh + k0, &LS[nb][0][w * 512]);
            gl_lds16(gAl + k0, &LS[nb][1][w * 512]);
            gl_lds16(gBh + k0, &LS[nb][2][w * 512]);
            gl_lds16(gBl + k0, &LS[nb][3][w * 512]);
        }
        bf16x8 ah0 = *(const bf16x8*)&LS[buf][0][oA0];
        bf16x8 ah1 = *(const bf16x8*)&LS[buf][0][oA1];
        bf16x8 al0 = *(const bf16x8*)&LS[buf][1][oA0];
        bf16x8 al1 = *(const bf16x8*)&LS[buf][1][oA1];
        bf16x8 bh0 = *(const bf16x8*)&LS[buf][2][oB0];
        bf16x8 bh1 = *(const bf16x8*)&LS[buf][2][oB1];
        bf16x8 bl0 = *(const bf16x8*)&LS[buf][3][oB0];
        bf16x8 bl1 = *(const bf16x8*)&LS[buf][3][oB1];
        a00 = __builtin_amdgcn_mfma_f32_16x16x32_bf16(ah0, bh0, a00, 0, 0, 0);
        a01 = __builtin_amdgcn_mfma_f32_16x16x32_bf16(ah0, bh1, a01, 0, 0, 0);
        a10 = __builtin_amdgcn_mfma_f32_16x16x32_bf16(ah1, bh0, a10, 0, 0, 0);
        a11 = __builtin_amdgcn_mfma_f32_16x16x32_bf16(ah1, bh1, a11, 0, 0, 0);
        a00 = __builtin_amdgcn_mfma_f32_16x16x32_bf16(ah0, bl0, a00, 0, 0, 0);
        a01 = __builtin_amdgcn_mfma_f32_16x16x32_bf16(ah0, bl1, a01, 0, 0, 0);
        a10 = __builtin_amdgcn_mfma_f32_16x16x32_bf16(ah1, bl0, a10, 0, 0, 0);
        a11 = __builtin_amdgcn_mfma_f32_16x16x32_bf16(ah1, bl1, a11, 0, 0, 0);
        a00 = __builtin_amdgcn_mfma_f32_16x16x32_bf16(al0, bh0, a00, 0, 0, 0);
        a01 = __builtin_amdgcn_mfma_f32_16x16x32_bf16(al0, bh1, a01, 0, 0, 0);
        a10 = __builtin_amdgcn_mfma_f32_16x16x32_bf16(al1, bh0, a10, 0, 0, 0);
        a11 = __builtin_amdgcn_mfma_f32_16x16x32_bf16(al1, bh1, a11, 0, 0, 0);
        __syncthreads();
    }

    const f32x4* accs[2][2] = {{&a00, &a01}, {&a10, &a11}};
    float* tile = (float*)LS;   // reuse: 64x65 floats = 16.6 KB

    if (gxp) {
        // ux = m .* gx at natural position; transpose via LDS; write uxT split
        short* oh = Ch_ + (size_t)zz * CH;
        short* ol = Cl_ + (size_t)zz * CH;
#pragma unroll
        for (int q = 0; q < 2; ++q)
#pragma unroll
            for (int pp = 0; pp < 2; ++pp)
#pragma unroll
                for (int rr = 0; rr < 4; ++rr) {
                    int r = wr * 32 + lc * 4 + q * 16 + rr;
                    int c = wc * 32 + pp * 16 + lr;
                    float v = (*accs[q][pp])[rr] * mz[(size_t)(m0 + r) * 512 + n0 + c];
                    tile[c * 65 + r] = v;
                }
        __syncthreads();
#pragma unroll
        for (int pass = 0; pass < 16; ++pass) {
            int j = pass * 4 + (tid >> 6);
            int i = tid & 63;
            float v = tile[j * 65 + i];
            int o = (n0 + j) * 512 + m0 + i;
            split_store(v, oh + o, ol + o);
        }
    } else {
        // uyT = gyT .* m^T : LDS-transpose the m tile, multiply, natural write
        short* oh = Dh_ + (size_t)zz * CH;
        short* ol = Dl_ + (size_t)zz * CH;
#pragma unroll
        for (int pass = 0; pass < 16; ++pass) {
            int i = pass * 4 + (tid >> 6);
            int j = tid & 63;
            tile[j * 65 + i] = mz[(size_t)(n0 + i) * 512 + m0 + j];
        }
        __syncthreads();
#pragma unroll
        for (int q = 0; q < 2; ++q)
#pragma unroll
            for (int pp = 0; pp < 2; ++pp)
#pragma unroll
                for (int rr = 0; rr < 4; ++rr) {
                    int r = wr * 32 + lc * 4 + q * 16 + rr;
                    int c = wc * 32 + pp * 16 + lr;
                    float v = (*accs[q][pp])[rr] * tile[r * 65 + c];
                    int o = (m0 + r) * 512 + n0 + c;
                    split_store(v, oh + o, ol + o);
                }
    }
}

// ---------------- L3 fused: GxT & GyT in one block + napply epilogue --------
__global__ __launch_bounds__(256) void gemm_l3(
    const short* __restrict__ Msh, const short* __restrict__ Msl,
    const short* __restrict__ Mch, const short* __restrict__ Mcl,
    const short* __restrict__ Ph, const short* __restrict__ Pl,
    const short* __restrict__ Qh, const short* __restrict__ Ql,
    short* __restrict__ Oh_, short* __restrict__ Ol_)
{
    __shared__ short LS[2][8][2048];   // Msh,Msl,Mch,Mcl,Ph,Pl,Qh,Ql
    int z = blockIdx.z;
    const short* ph = Ph + (size_t)z * CH;
    const short* pl = Pl + (size_t)z * CH;
    const short* qh = Qh + (size_t)z * CH;
    const short* ql = Ql + (size_t)z * CH;
    short* oh = Oh_ + (size_t)z * CH;
    short* ol = Ol_ + (size_t)z * CH;

    int tid = threadIdx.x;
    int l = tid & 63, w = tid >> 6;
    int m0 = blockIdx.y * 64, n0 = blockIdx.x * 64;

    int p = w * 64 + l;
    STAGE_IDX(p, srow, sc)
    size_t ga = (size_t)(m0 + srow) * 512 + 8 * sc;
    size_t gb = (size_t)(n0 + srow) * 512 + 8 * sc;
    const short* g0 = Msh + ga; const short* g1 = Msl + ga;
    const short* g2 = Mch + ga; const short* g3 = Mcl + ga;
    const short* g4 = ph + gb;  const short* g5 = pl + gb;
    const short* g6 = qh + gb;  const short* g7 = ql + gb;

    int wr = w >> 1, wc = w & 1;
    int lr = l & 15, lc = l >> 4;
    int rA0 = wr * 32 + lr, rA1 = rA0 + 16;
    int rB0 = wc * 32 + lr, rB1 = rB0 + 16;
    int oA0 = FRAG_OFF(rA0, lc), oA1 = FRAG_OFF(rA1, lc);
    int oB0 = FRAG_OFF(rB0, lc), oB1 = FRAG_OFF(rB1, lc);

    f32x4 x00 = {0,0,0,0}, x01 = x00, x10 = x00, x11 = x00;
    f32x4 y00 = x00, y01 = x00, y10 = x00, y11 = x00;

#define STAGE_L3(nb, k0) \
    gl_lds16(g0 + (k0), &LS[nb][0][w * 512]); \
    gl_lds16(g1 + (k0), &LS[nb][1][w * 512]); \
    gl_lds16(g2 + (k0), &LS[nb][2][w * 512]); \
    gl_lds16(g3 + (k0), &LS[nb][3][w * 512]); \
    gl_lds16(g4 + (k0), &LS[nb][4][w * 512]); \
    gl_lds16(g5 + (k0), &LS[nb][5][w * 512]); \
    gl_lds16(g6 + (k0), &LS[nb][6][w * 512]); \
    gl_lds16(g7 + (k0), &LS[nb][7][w * 512]);

    STAGE_L3(0, 0)
    __syncthreads();

    for (int step = 0; step < 16; ++step) {
        int buf = step & 1;
        if (step < 15) {
            int k0 = (step + 1) * 32;
            int nb = buf ^ 1;
            STAGE_L3(nb, k0)
        }
        bf16x8 sh0 = *(const bf16x8*)&LS[buf][0][oA0];
        bf16x8 sh1 = *(const bf16x8*)&LS[buf][0][oA1];
        bf16x8 sl0 = *(const bf16x8*)&LS[buf][1][oA0];
        bf16x8 sl1 = *(const bf16x8*)&LS[buf][1][oA1];
        bf16x8 phf0 = *(const bf16x8*)&LS[buf][4][oB0];
        bf16x8 phf1 = *(const bf16x8*)&LS[buf][4][oB1];
        bf16x8 plf0 = *(const bf16x8*)&LS[buf][5][oB0];
        bf16x8 plf1 = *(const bf16x8*)&LS[buf][5][oB1];
        x00 = __builtin_amdgcn_mfma_f32_16x16x32_bf16(sh0, phf0, x00, 0, 0, 0);
        x01 = __builtin_amdgcn_mfma_f32_16x16x32_bf16(sh0, phf1, x01, 0, 0, 0);
        x10 = __builtin_amdgcn_mfma_f32_16x16x32_bf16(sh1, phf0, x10, 0, 0, 0);
        x11 = __builtin_amdgcn_mfma_f32_16x16x32_bf16(sh1, phf1, x11, 0, 0, 0);
        x00 = __builtin_amdgcn_mfma_f32_16x16x32_bf16(sh0, plf0, x00, 0, 0, 0);
        x01 = __builtin_amdgcn_mfma_f32_16x16x32_bf16(sh0, plf1, x01, 0, 0, 0);
        x10 = __builtin_amdgcn_mfma_f32_16x16x32_bf16(sh1, plf0, x10, 0, 0, 0);
        x11 = __builtin_amdgcn_mfma_f32_16x16x32_bf16(sh1, plf1, x11, 0, 0, 0);
        x00 = __builtin_amdgcn_mfma_f32_16x16x32_bf16(sl0, phf0, x00, 0, 0, 0);
        x01 = __builtin_amdgcn_mfma_f32_16x16x32_bf16(sl0, phf1, x01, 0, 0, 0);
        x10 = __builtin_amdgcn_mfma_f32_16x16x32_bf16(sl1, phf0, x10, 0, 0, 0);
        x11 = __builtin_amdgcn_mfma_f32_16x16x32_bf16(sl1, phf1, x11, 0, 0, 0);
        bf16x8 ch0 = *(const bf16x8*)&LS[buf][2][oA0];
        bf16x8 ch1 = *(const bf16x8*)&LS[buf][2][oA1];
        bf16x8 cl0 = *(const bf16x8*)&LS[buf][3][oA0];
        bf16x8 cl1 = *(const bf16x8*)&LS[buf][3][oA1];
        bf16x8 qhf0 = *(const bf16x8*)&LS[buf][6][oB0];
        bf16x8 qhf1 = *(const bf16x8*)&LS[buf][6][oB1];
        bf16x8 qlf0 = *(const bf16x8*)&LS[buf][7][oB0];
        bf16x8 qlf1 = *(const bf16x8*)&LS[buf][7][oB1];
        y00 = __builtin_amdgcn_mfma_f32_16x16x32_bf16(ch0, qhf0, y00, 0, 0, 0);
        y01 = __builtin_amdgcn_mfma_f32_16x16x32_bf16(ch0, qhf1, y01, 0, 0, 0);
        y10 = __builtin_amdgcn_mfma_f32_16x16x32_bf16(ch1, qhf0, y10, 0, 0, 0);
        y11 = __builtin_amdgcn_mfma_f32_16x16x32_bf16(ch1, qhf1, y11, 0, 0, 0);
        y00 = __builtin_amdgcn_mfma_f32_16x16x32_bf16(ch0, qlf0, y00, 0, 0, 0);
        y01 = __builtin_amdgcn_mfma_f32_16x16x32_bf16(ch0, qlf1, y01, 0, 0, 0);
        y10 = __builtin_amdgcn_mfma_f32_16x16x32_bf16(ch1, qlf0, y10, 0, 0, 0);
        y11 = __builtin_amdgcn_mfma_f32_16x16x32_bf16(ch1, qlf1, y11, 0, 0, 0);
        y00 = __builtin_amdgcn_mfma_f32_16x16x32_bf16(cl0, qhf0, y00, 0, 0, 0);
        y01 = __builtin_amdgcn_mfma_f32_16x16x32_bf16(cl0, qhf1, y01, 0, 0, 0);
        y10 = __builtin_amdgcn_mfma_f32_16x16x32_bf16(cl1, qhf0, y10, 0, 0, 0);
        y11 = __builtin_amdgcn_mfma_f32_16x16x32_bf16(cl1, qhf1, y11, 0, 0, 0);
        __syncthreads();
    }
#undef STAGE_L3

    int crow = m0 + wr * 32 + lc * 4;   // v
    int ccol = n0 + wc * 32 + lr;       // u
    const f32x4* xs[2][2] = {{&x00, &x01}, {&x10, &x11}};
    const f32x4* ys[2][2] = {{&y00, &y01}, {&y10, &y11}};
#pragma unroll
    for (int q = 0; q < 2; ++q)
#pragma unroll
        for (int pp = 0; pp < 2; ++pp) {
            int u = ccol + pp * 16;
            float eu = (u ? 2.0f : 1.0f) * kInvHW;
#pragma unroll
            for (int rr = 0; rr < 4; ++rr) {
                int v = crow + q * 16 + rr;
                float gx = (*xs[q][pp])[rr];
                float gy = (*ys[q][pp])[rr];
                float num = kPiOver512 * ((float)v * gx + (float)u * gy);
                float den = 1e-10f - kPi2Norm * (float)(u * u + v * v);
                float eps = (v ? 2.0f : 1.0f) * eu;
                int o = v * 512 + u;
                split_store(eps * num / den, oh + o, ol + o);
            }
        }
}

// ---------------- d = s-t: nat + transposed split, fused t/(1-m) partials ---
__global__ __launch_bounds__(256) void diff_split_red(
    const float* __restrict__ s, const float* __restrict__ t, const float* __restrict__ m,
    short* __restrict__ dnh, short* __restrict__ dnl,
    short* __restrict__ dth, short* __restrict__ dtl,
    float* __restrict__ mt, float* __restrict__ mi)
{
    __shared__ float tile[32][33];
    __shared__ float red[512];
    int z = blockIdx.z;
    const float* sz = s + (size_t)z * CH;
    const float* tz = t + (size_t)z * CH;
    const float* mz = m + (size_t)z * CH;
    short* nh = dnh + (size_t)z * CH; short* nl = dnl + (size_t)z * CH;
    short* th = dth + (size_t)z * CH; short* tl = dtl + (size_t)z * CH;
    int bx = blockIdx.x * 32, by = blockIdx.y * 32;
    int tx = threadIdx.x & 31, ty = threadIdx.x >> 5;
    float accT = 0.f, accI = 0.f;
    for (int r = ty; r < 32; r += 8) {
        int idx = (by + r) * 512 + bx + tx;
        float tv = tz[idx];
        float d = sz[idx] - tv;
        tile[r][tx] = d;
        split_store(d, nh + idx, nl + idx);
        accT += tv;
        if (z < 3) accI += 1.0f - mz[idx];
    }
    __syncthreads();
    for (int r = ty; r < 32; r += 8) {
        int o = (bx + r) * 512 + by + tx;
        split_store(tile[tx][r], th + o, tl + o);
    }
    int tid = threadIdx.x;
    red[tid] = accT; red[256 + tid] = accI;
    __syncthreads();
    for (int s2 = 128; s2 > 0; s2 >>= 1) {
        if (tid < s2) { red[tid] += red[tid + s2]; red[256 + tid] += red[256 + tid + s2]; }
        __syncthreads();
    }
    if (tid == 0) {
        int tileid = blockIdx.y * 16 + blockIdx.x;
        mt[z * 256 + tileid] = red[0];
        if (z < 3) mi[z * 256 + tileid] = red[256];
    }
}

// ---------------- final: out = t + U + shift[z] -----------------------------
__global__ __launch_bounds__(256) void final_out(
    const float* __restrict__ t, const float* __restrict__ U,
    const float* __restrict__ part, float* __restrict__ out)
{
    __shared__ float mtv[6], wmuv[3];
    int tid = threadIdx.x;
    if (tid < 6) {
        float s2 = 0.f;
        for (int k = 0; k < 256; ++k) s2 += part[tid * 256 + k];
        mtv[tid] = s2 * (1.0f / (float)CH);
    }
    if (tid >= 8 && tid < 11) {
        int c = tid - 8;
        float si = 0.f, su = 0.f;
        for (int k = 0; k < 256; ++k) si += part[1536 + c * 256 + k];
        for (int k = 0; k < 64; ++k) su += part[2304 + c * 64 + k];
        wmuv[c] = su / si;
    }
    __syncthreads();
    int n4 = NTOT / 4;
    for (int i = blockIdx.x * blockDim.x + tid; i < n4; i += gridDim.x * blockDim.x) {
        int z = i >> 16;
        int c = z % 3;
        float sh = -mtv[z] + mtv[c] - wmuv[c];
        float4 tv = ((const float4*)t)[i];
        float4 uv = ((const float4*)U)[i];
        ((float4*)out)[i] = make_float4(tv.x + uv.x + sh, tv.y + uv.y + sh,
                                        tv.z + uv.z + sh, tv.w + uv.w + sh);
    }
}

extern "C" void kernel_launch(void* const* d_in, const int* in_sizes, int n_in,
                              void* d_out, int out_size, void* d_ws, size_t ws_size,
                              hipStream_t stream) {
    const float* t = (const float*)d_in[0];
    const float* s = (const float*)d_in[1];
    const float* m = (const float*)d_in[2];
    float* out = (float*)d_out;
    float* F = (float*)d_ws;
    if (ws_size < (size_t)(35 * CH + 4096) * sizeof(float)) return;

    // tables: 8 x CH shorts = F[0 .. 4CH)
    short* T = (short*)F;
    short *Mc_h = T,                *Mc_l = T + (size_t)CH,
          *Ms_h = T + 2*(size_t)CH, *Ms_l = T + 3*(size_t)CH,
          *McT_h = T + 4*(size_t)CH,*McT_l = T + 5*(size_t)CH,
          *GT_h = T + 6*(size_t)CH, *GT_l = T + 7*(size_t)CH;
    // four bf16 banks, each [hi 6CH][lo 6CH]
    short* Ah = (short*)(F + 4  * (size_t)CH);  short* Al = Ah + 6 * (size_t)CH;
    short* Bh = (short*)(F + 10 * (size_t)CH);  short* Bl = Bh + 6 * (size_t)CH;
    short* Ch_ = (short*)(F + 16 * (size_t)CH); short* Cl_ = Ch_ + 6 * (size_t)CH;
    short* Dh_ = (short*)(F + 22 * (size_t)CH); short* Dl_ = Dh_ + 6 * (size_t)CH;
    float* F0  = F + 28 * (size_t)CH;           // 6 CH f32 (U)
    float* part = F + 34 * (size_t)CH;          // partials

    build_tables<<<1024, 256, 0, stream>>>(Mc_h, Mc_l, Ms_h, Ms_l,
                                           McT_h, McT_l, GT_h, GT_l);

    // d = s-t -> A (nat), B (transposed); + t / (1-m) partials
    diff_split_red<<<dim3(16, 16, 6), 256, 0, stream>>>(s, t, m, Ah, Al, Bh, Bl,
                                                        part, part + 1536);

    // L1 fused: gx/gyT GEMMs + mask(+transpose) -> uxT (C), uyT (D)
    gemm_l1<<<dim3(8, 8, 12), 256, 0, stream>>>(Ah, Al, Bh, Bl, GT_h, GT_l, m,
                                                Ch_, Cl_, Dh_, Dl_);

    // L2: P = Mc~uxT -> A (split) ; Q = Ms~uyT -> B (split)
    gemm_tn<1><<<dim3(8, 8, 12), 256, 0, stream>>>(
        Mc_h, Mc_l, 0, Ch_, Cl_, CH, nullptr, Ah, Al, CH,
        Ms_h, Ms_l, 0, Dh_, Dl_, CH, nullptr, Bh, Bl, CH, 6, nullptr, nullptr);

    // L3 fused: GxT = Ms~P & GyT = Mc~Q + napply -> npT (C, split)
    gemm_l3<<<dim3(8, 8, 6), 256, 0, stream>>>(Ms_h, Ms_l, Mc_h, Mc_l,
                                               Ah, Al, Bh, Bl, Ch_, Cl_);

    // L4: R = McT~npT -> D (split)
    gemm_tn<1><<<dim3(8, 8, 6), 256, 0, stream>>>(
        McT_h, McT_l, 0, Ch_, Cl_, CH, nullptr, Dh_, Dl_, CH,
        McT_h, McT_l, 0, Ch_, Cl_, CH, nullptr, Dh_, Dl_, CH, 6, nullptr, nullptr);

    // L5: U = R~McT -> F0 + masked-dot partials
    gemm_tn<2><<<dim3(8, 8, 6), 256, 0, stream>>>(
        Dh_, Dl_, CH, McT_h, McT_l, 0, F0, nullptr, nullptr, CH,
        Dh_, Dl_, CH, McT_h, McT_l, 0, F0, nullptr, nullptr, CH, 6, m, part + 2304);

    // out = t + U + shift
    final_out<<<768, 256, 0, stream>>>(t, F0, part, out);
}

// Round 6
// 70.394 us; speedup vs baseline: 6.7276x; 1.5417x over previous
//
#include <hip/hip_runtime.h>

// Poisson composition via real DCT/DST algebra on matrix cores, single-fp16
// MFMA (f32 accumulate). 8 launches. G in closed form:
//   G[i][j] = (pi/1024)*(h(i+j+1) + h(j-i)),  h(k) = (-1)^k * cot(pi*k/1024).
// Chain (TN GEMMs, C[m][n] = sum_k A[m][k]*Bt[n][k], fp16 operands):
//   d=s-t (nat->A, T->B) ; L1: gx=d~G, gyT=dT~G, epilogue mask(+T) -> uxT(C), uyT(D)
//   L2: P=Mc~uxT -> A, Q=Ms~uyT -> B   (fp16 epilogue)
//   L3fused: GxT=Ms~P & GyT=Mc~Q, epilogue napply -> npT(C)
//   L4: R=McT~npT -> D ; L5: U=R~McT -> F0 (+ masked-dot partials)
//   final_out: out = t + U + shift[z].

#define CH 262144   // 512*512
#define NCH 6
#define NTOT (NCH*CH)

typedef _Float16 f16x8 __attribute__((ext_vector_type(8)));
typedef float f32x4  __attribute__((ext_vector_type(4)));

static constexpr float kPi        = 3.14159265358979323846f;
static constexpr float kPiOver512 = 0.006135923151542565f;   // pi/512
static constexpr float kPi2Norm   = 3.7649933338155804e-05f; // pi^2/512^2
static constexpr float kInvHW     = 3.814697265625e-06f;     // 1/512^2

__device__ __forceinline__ void hst(float v, short* p) {
    *reinterpret_cast<_Float16*>(p) = (_Float16)v;
}

// ---------------- tables: Mc, Ms, McT, GT (closed form), fp16 ---------------
__device__ __forceinline__ float hfun(int k) {
    if (k == 0) return 0.f;
    float sgn = 1.f;
    if (k < 0) { k = -k; sgn = -1.f; }
    if (k > 512) { k = 1024 - k; sgn = -sgn; }
    float sv, cv;
    sincosf((float)k * (kPi / 1024.0f), &sv, &cv);
    float v = cv / sv;
    if (k & 1) v = -v;
    return sgn * v;
}

__global__ void build_tables(short* Mc, short* Ms, short* McT, short* GT) {
    int idx = blockIdx.x * blockDim.x + threadIdx.x;
    if (idx >= CH) return;
    int a = idx >> 9, b = idx & 511;
    int p1 = (a * (2 * b + 1)) & 2047;
    float s1, c1; sincosf((float)p1 * (kPi / 1024.0f), &s1, &c1);
    hst(c1, Mc + idx);
    hst(s1, Ms + idx);
    int p2 = (b * (2 * a + 1)) & 2047;
    float s2, c2; sincosf((float)p2 * (kPi / 1024.0f), &s2, &c2);
    hst(c2, McT + idx);
    float g = (kPi / 1024.0f) * (hfun(a + b + 1) + hfun(a - b));
    hst(g, GT + idx);
}

// ---------------- shared GEMM machinery (BK=64) ----------------
__device__ __forceinline__ void gl_lds16(const short* g, const short* l) {
    __builtin_amdgcn_global_load_lds(
        (const __attribute__((address_space(1))) void*)g,
        (__attribute__((address_space(3))) void*)l, 16, 0, 0);
}

// LDS tile: 64 rows x 64 k fp16 = 8 KB. Row r, k-slot s (8 fp16 each) holds
// global kchunk s ^ (r&7). Staging: wave w pass0 rows w*8..+7, pass1 +32.
// Frag read offset for (row r, logical kchunk j):
#define FOFF(r, j) (((r) << 6) + 8 * ((j) ^ ((r) & 7)))

#define MFMA16(a, b, c) __builtin_amdgcn_mfma_f32_16x16x32_f16(a, b, c, 0, 0, 0)

// OM: 1 = fp16 out; 2 = fp32 C + masked-dot partials
template<int OM>
__global__ __launch_bounds__(256) void gemm_tn(
    const short* __restrict__ A0, int sA0, const short* __restrict__ B0, int sB0,
    float* __restrict__ Cf0, short* __restrict__ O0, int sC0,
    const short* __restrict__ A1, int sA1, const short* __restrict__ B1, int sB1,
    float* __restrict__ Cf1, short* __restrict__ O1, int sC1,
    int zsplit, const float* __restrict__ msk, float* __restrict__ redp)
{
    __shared__ short LS[2][2][4096];   // [buf][A,B][64x64 fp16]
    int z = blockIdx.z;
    const short *A, *B; float* Cf; short* O;
    if (z < zsplit) {
        A = A0 + (size_t)z * sA0; B = B0 + (size_t)z * sB0;
        Cf = Cf0 ? Cf0 + (size_t)z * sC0 : nullptr;
        O  = O0 ? O0 + (size_t)z * sC0 : nullptr;
    } else {
        int zz = z - zsplit;
        A = A1 + (size_t)zz * sA1; B = B1 + (size_t)zz * sB1;
        Cf = Cf1 ? Cf1 + (size_t)zz * sC1 : nullptr;
        O  = O1 ? O1 + (size_t)zz * sC1 : nullptr;
    }
    int tid = threadIdx.x;
    int l = tid & 63, w = tid >> 6;
    int m0 = blockIdx.y * 64, n0 = blockIdx.x * 64;

    int srow = w * 8 + (l >> 3);
    int skc  = (l & 7) ^ ((l >> 3) & 7);
    const short* gA = A + (size_t)(m0 + srow) * 512 + 8 * skc;
    const short* gB = B + (size_t)(n0 + srow) * 512 + 8 * skc;

    int wr = w >> 1, wc = w & 1;
    int lr = l & 15, lc = l >> 4;
    int rA0 = wr * 32 + lr, rA1 = rA0 + 16;
    int rB0 = wc * 32 + lr, rB1 = rB0 + 16;

    f32x4 a00 = {0,0,0,0}, a01 = a00, a10 = a00, a11 = a00;

#define STAGE_AB(nb, k0) \
    gl_lds16(gA + (k0), &LS[nb][0][w * 512]); \
    gl_lds16(gA + (k0) + 32 * 512, &LS[nb][0][w * 512 + 2048]); \
    gl_lds16(gB + (k0), &LS[nb][1][w * 512]); \
    gl_lds16(gB + (k0) + 32 * 512, &LS[nb][1][w * 512 + 2048]);

    STAGE_AB(0, 0)
    __syncthreads();

    for (int step = 0; step < 8; ++step) {
        int buf = step & 1;
        if (step < 7) { STAGE_AB(buf ^ 1, (step + 1) * 64) }
#pragma unroll
        for (int ks = 0; ks < 2; ++ks) {
            int j = lc + 4 * ks;
            f16x8 va0 = *(const f16x8*)&LS[buf][0][FOFF(rA0, j)];
            f16x8 va1 = *(const f16x8*)&LS[buf][0][FOFF(rA1, j)];
            f16x8 vb0 = *(const f16x8*)&LS[buf][1][FOFF(rB0, j)];
            f16x8 vb1 = *(const f16x8*)&LS[buf][1][FOFF(rB1, j)];
            a00 = MFMA16(va0, vb0, a00);
            a01 = MFMA16(va0, vb1, a01);
            a10 = MFMA16(va1, vb0, a10);
            a11 = MFMA16(va1, vb1, a11);
        }
        __syncthreads();
    }
#undef STAGE_AB

    int crow = m0 + wr * 32 + lc * 4;
    int ccol = n0 + wc * 32 + lr;
    const f32x4* accs[2][2] = {{&a00, &a01}, {&a10, &a11}};
    float lsum = 0.f;
#pragma unroll
    for (int q = 0; q < 2; ++q)
#pragma unroll
        for (int pp = 0; pp < 2; ++pp)
#pragma unroll
            for (int rr = 0; rr < 4; ++rr) {
                int idx = (crow + q * 16 + rr) * 512 + ccol + pp * 16;
                float v = (*accs[q][pp])[rr];
                if (OM == 1) {
                    hst(v, O + idx);
                } else {
                    Cf[idx] = v;
                    lsum += v * (1.0f - msk[(size_t)z * CH + idx]);
                }
            }
    if (OM == 2) {
        float* red = (float*)LS;
        red[tid] = lsum;
        __syncthreads();
        for (int s2 = 128; s2 > 0; s2 >>= 1) {
            if (tid < s2) red[tid] += red[tid + s2];
            __syncthreads();
        }
        if (tid == 0) redp[z * 64 + blockIdx.y * 8 + blockIdx.x] = red[0];
    }
}

// ---------------- L1 fused: gradients + mask + transpose ----------------
__global__ __launch_bounds__(256) void gemm_l1(
    const short* __restrict__ dn, const short* __restrict__ dt,
    const short* __restrict__ GT, const float* __restrict__ msk,
    short* __restrict__ C_, short* __restrict__ D_)
{
    __shared__ short LS[2][2][4096];
    int z = blockIdx.z;
    bool gxp = z < 6;
    int zz = gxp ? z : z - 6;
    const short* A = (gxp ? dn : dt) + (size_t)zz * CH;
    const float* mz = msk + (size_t)zz * CH;

    int tid = threadIdx.x;
    int l = tid & 63, w = tid >> 6;
    int m0 = blockIdx.y * 64, n0 = blockIdx.x * 64;

    int srow = w * 8 + (l >> 3);
    int skc  = (l & 7) ^ ((l >> 3) & 7);
    const short* gA = A + (size_t)(m0 + srow) * 512 + 8 * skc;
    const short* gB = GT + (size_t)(n0 + srow) * 512 + 8 * skc;

    int wr = w >> 1, wc = w & 1;
    int lr = l & 15, lc = l >> 4;
    int rA0 = wr * 32 + lr, rA1 = rA0 + 16;
    int rB0 = wc * 32 + lr, rB1 = rB0 + 16;

    f32x4 a00 = {0,0,0,0}, a01 = a00, a10 = a00, a11 = a00;

#define STAGE_AB(nb, k0) \
    gl_lds16(gA + (k0), &LS[nb][0][w * 512]); \
    gl_lds16(gA + (k0) + 32 * 512, &LS[nb][0][w * 512 + 2048]); \
    gl_lds16(gB + (k0), &LS[nb][1][w * 512]); \
    gl_lds16(gB + (k0) + 32 * 512, &LS[nb][1][w * 512 + 2048]);

    STAGE_AB(0, 0)
    __syncthreads();

    for (int step = 0; step < 8; ++step) {
        int buf = step & 1;
        if (step < 7) { STAGE_AB(buf ^ 1, (step + 1) * 64) }
#pragma unroll
        for (int ks = 0; ks < 2; ++ks) {
            int j = lc + 4 * ks;
            f16x8 va0 = *(const f16x8*)&LS[buf][0][FOFF(rA0, j)];
            f16x8 va1 = *(const f16x8*)&LS[buf][0][FOFF(rA1, j)];
            f16x8 vb0 = *(const f16x8*)&LS[buf][1][FOFF(rB0, j)];
            f16x8 vb1 = *(const f16x8*)&LS[buf][1][FOFF(rB1, j)];
            a00 = MFMA16(va0, vb0, a00);
            a01 = MFMA16(va0, vb1, a01);
            a10 = MFMA16(va1, vb0, a10);
            a11 = MFMA16(va1, vb1, a11);
        }
        __syncthreads();
    }
#undef STAGE_AB

    const f32x4* accs[2][2] = {{&a00, &a01}, {&a10, &a11}};
    float* tile = (float*)LS;   // 64x65 floats = 16.6 KB

    if (gxp) {
        // ux = m .* gx; transpose via LDS; write uxT fp16
        short* o = C_ + (size_t)zz * CH;
#pragma unroll
        for (int q = 0; q < 2; ++q)
#pragma unroll
            for (int pp = 0; pp < 2; ++pp)
#pragma unroll
                for (int rr = 0; rr < 4; ++rr) {
                    int r = wr * 32 + lc * 4 + q * 16 + rr;
                    int c = wc * 32 + pp * 16 + lr;
                    float v = (*accs[q][pp])[rr] * mz[(size_t)(m0 + r) * 512 + n0 + c];
                    tile[c * 65 + r] = v;
                }
        __syncthreads();
#pragma unroll
        for (int pass = 0; pass < 16; ++pass) {
            int jj = pass * 4 + (tid >> 6);
            int ii = tid & 63;
            hst(tile[jj * 65 + ii], o + (n0 + jj) * 512 + m0 + ii);
        }
    } else {
        // uyT = gyT .* m^T : LDS-transpose m tile, multiply, natural write
        short* o = D_ + (size_t)zz * CH;
#pragma unroll
        for (int pass = 0; pass < 16; ++pass) {
            int ii = pass * 4 + (tid >> 6);
            int jj = tid & 63;
            tile[jj * 65 + ii] = mz[(size_t)(n0 + ii) * 512 + m0 + jj];
        }
        __syncthreads();
#pragma unroll
        for (int q = 0; q < 2; ++q)
#pragma unroll
            for (int pp = 0; pp < 2; ++pp)
#pragma unroll
                for (int rr = 0; rr < 4; ++rr) {
                    int r = wr * 32 + lc * 4 + q * 16 + rr;
                    int c = wc * 32 + pp * 16 + lr;
                    float v = (*accs[q][pp])[rr] * tile[r * 65 + c];
                    hst(v, o + (m0 + r) * 512 + n0 + c);
                }
    }
}

// ---------------- L3 fused: GxT & GyT + napply epilogue ----------------
__global__ __launch_bounds__(256) void gemm_l3(
    const short* __restrict__ Ms, const short* __restrict__ Mc,
    const short* __restrict__ P, const short* __restrict__ Q,
    short* __restrict__ O_)
{
    __shared__ short LS[2][4][4096];   // Ms, Mc, P, Q
    int z = blockIdx.z;
    const short* pz = P + (size_t)z * CH;
    const short* qz = Q + (size_t)z * CH;
    short* o = O_ + (size_t)z * CH;

    int tid = threadIdx.x;
    int l = tid & 63, w = tid >> 6;
    int m0 = blockIdx.y * 64, n0 = blockIdx.x * 64;

    int srow = w * 8 + (l >> 3);
    int skc  = (l & 7) ^ ((l >> 3) & 7);
    size_t ga = (size_t)(m0 + srow) * 512 + 8 * skc;
    size_t gb = (size_t)(n0 + srow) * 512 + 8 * skc;
    const short* g0 = Ms + ga;
    const short* g1 = Mc + ga;
    const short* g2 = pz + gb;
    const short* g3 = qz + gb;

    int wr = w >> 1, wc = w & 1;
    int lr = l & 15, lc = l >> 4;
    int rA0 = wr * 32 + lr, rA1 = rA0 + 16;
    int rB0 = wc * 32 + lr, rB1 = rB0 + 16;

    f32x4 x00 = {0,0,0,0}, x01 = x00, x10 = x00, x11 = x00;
    f32x4 y00 = x00, y01 = x00, y10 = x00, y11 = x00;

#define STAGE_L3(nb, k0) \
    gl_lds16(g0 + (k0), &LS[nb][0][w * 512]); \
    gl_lds16(g0 + (k0) + 32 * 512, &LS[nb][0][w * 512 + 2048]); \
    gl_lds16(g1 + (k0), &LS[nb][1][w * 512]); \
    gl_lds16(g1 + (k0) + 32 * 512, &LS[nb][1][w * 512 + 2048]); \
    gl_lds16(g2 + (k0), &LS[nb][2][w * 512]); \
    gl_lds16(g2 + (k0) + 32 * 512, &LS[nb][2][w * 512 + 2048]); \
    gl_lds16(g3 + (k0), &LS[nb][3][w * 512]); \
    gl_lds16(g3 + (k0) + 32 * 512, &LS[nb][3][w * 512 + 2048]);

    STAGE_L3(0, 0)
    __syncthreads();

    for (int step = 0; step < 8; ++step) {
        int buf = step & 1;
        if (step < 7) { STAGE_L3(buf ^ 1, (step + 1) * 64) }
#pragma unroll
        for (int ks = 0; ks < 2; ++ks) {
            int j = lc + 4 * ks;
            f16x8 s0 = *(const f16x8*)&LS[buf][0][FOFF(rA0, j)];
            f16x8 s1 = *(const f16x8*)&LS[buf][0][FOFF(rA1, j)];
            f16x8 p0 = *(const f16x8*)&LS[buf][2][FOFF(rB0, j)];
            f16x8 p1 = *(const f16x8*)&LS[buf][2][FOFF(rB1, j)];
            x00 = MFMA16(s0, p0, x00);
            x01 = MFMA16(s0, p1, x01);
            x10 = MFMA16(s1, p0, x10);
            x11 = MFMA16(s1, p1, x11);
            f16x8 c0 = *(const f16x8*)&LS[buf][1][FOFF(rA0, j)];
            f16x8 c1 = *(const f16x8*)&LS[buf][1][FOFF(rA1, j)];
            f16x8 q0 = *(const f16x8*)&LS[buf][3][FOFF(rB0, j)];
            f16x8 q1 = *(const f16x8*)&LS[buf][3][FOFF(rB1, j)];
            y00 = MFMA16(c0, q0, y00);
            y01 = MFMA16(c0, q1, y01);
            y10 = MFMA16(c1, q0, y10);
            y11 = MFMA16(c1, q1, y11);
        }
        __syncthreads();
    }
#undef STAGE_L3

    int crow = m0 + wr * 32 + lc * 4;   // v
    int ccol = n0 + wc * 32 + lr;       // u
    const f32x4* xs[2][2] = {{&x00, &x01}, {&x10, &x11}};
    const f32x4* ys[2][2] = {{&y00, &y01}, {&y10, &y11}};
#pragma unroll
    for (int q = 0; q < 2; ++q)
#pragma unroll
        for (int pp = 0; pp < 2; ++pp) {
            int u = ccol + pp * 16;
            float eu = (u ? 2.0f : 1.0f) * kInvHW;
#pragma unroll
            for (int rr = 0; rr < 4; ++rr) {
                int v = crow + q * 16 + rr;
                float gx = (*xs[q][pp])[rr];
                float gy = (*ys[q][pp])[rr];
                float num = kPiOver512 * ((float)v * gx + (float)u * gy);
                float den = 1e-10f - kPi2Norm * (float)(u * u + v * v);
                float eps = (v ? 2.0f : 1.0f) * eu;
                hst(eps * num / den, o + v * 512 + u);
            }
        }
}

// ---------------- d = s-t: nat + transposed fp16, fused partials ------------
__global__ __launch_bounds__(256) void diff_split_red(
    const float* __restrict__ s, const float* __restrict__ t, const float* __restrict__ m,
    short* __restrict__ dn, short* __restrict__ dt,
    float* __restrict__ mt, float* __restrict__ mi)
{
    __shared__ float tile[32][33];
    __shared__ float red[512];
    int z = blockIdx.z;
    const float* sz = s + (size_t)z * CH;
    const float* tz = t + (size_t)z * CH;
    const float* mz = m + (size_t)z * CH;
    short* nh = dn + (size_t)z * CH;
    short* th = dt + (size_t)z * CH;
    int bx = blockIdx.x * 32, by = blockIdx.y * 32;
    int tx = threadIdx.x & 31, ty = threadIdx.x >> 5;
    float accT = 0.f, accI = 0.f;
    for (int r = ty; r < 32; r += 8) {
        int idx = (by + r) * 512 + bx + tx;
        float tv = tz[idx];
        float d = sz[idx] - tv;
        tile[r][tx] = d;
        hst(d, nh + idx);
        accT += tv;
        if (z < 3) accI += 1.0f - mz[idx];
    }
    __syncthreads();
    for (int r = ty; r < 32; r += 8) {
        hst(tile[tx][r], th + (bx + r) * 512 + by + tx);
    }
    int tid = threadIdx.x;
    red[tid] = accT; red[256 + tid] = accI;
    __syncthreads();
    for (int s2 = 128; s2 > 0; s2 >>= 1) {
        if (tid < s2) { red[tid] += red[tid + s2]; red[256 + tid] += red[256 + tid + s2]; }
        __syncthreads();
    }
    if (tid == 0) {
        int tileid = blockIdx.y * 16 + blockIdx.x;
        mt[z * 256 + tileid] = red[0];
        if (z < 3) mi[z * 256 + tileid] = red[256];
    }
}

// ---------------- final: out = t + U + shift[z] -----------------------------
__global__ __launch_bounds__(256) void final_out(
    const float* __restrict__ t, const float* __restrict__ U,
    const float* __restrict__ part, float* __restrict__ out)
{
    __shared__ float mtv[6], wmuv[3];
    int tid = threadIdx.x;
    if (tid < 6) {
        float s2 = 0.f;
        for (int k = 0; k < 256; ++k) s2 += part[tid * 256 + k];
        mtv[tid] = s2 * (1.0f / (float)CH);
    }
    if (tid >= 8 && tid < 11) {
        int c = tid - 8;
        float si = 0.f, su = 0.f;
        for (int k = 0; k < 256; ++k) si += part[1536 + c * 256 + k];
        for (int k = 0; k < 64; ++k) su += part[2304 + c * 64 + k];
        wmuv[c] = su / si;
    }
    __syncthreads();
    int n4 = NTOT / 4;
    for (int i = blockIdx.x * blockDim.x + tid; i < n4; i += gridDim.x * blockDim.x) {
        int z = i >> 16;
        int c = z % 3;
        float sh = -mtv[z] + mtv[c] - wmuv[c];
        float4 tv = ((const float4*)t)[i];
        float4 uv = ((const float4*)U)[i];
        ((float4*)out)[i] = make_float4(tv.x + uv.x + sh, tv.y + uv.y + sh,
                                        tv.z + uv.z + sh, tv.w + uv.w + sh);
    }
}

extern "C" void kernel_launch(void* const* d_in, const int* in_sizes, int n_in,
                              void* d_out, int out_size, void* d_ws, size_t ws_size,
                              hipStream_t stream) {
    const float* t = (const float*)d_in[0];
    const float* s = (const float*)d_in[1];
    const float* m = (const float*)d_in[2];
    float* out = (float*)d_out;
    float* F = (float*)d_ws;
    if (ws_size < (size_t)(21 * CH + 4096) * sizeof(float)) return;

    // tables: 4 x CH fp16 = F[0 .. 2CH)
    short* T = (short*)F;
    short *Mc = T, *Ms = T + (size_t)CH, *McT = T + 2 * (size_t)CH, *GT = T + 3 * (size_t)CH;
    // four fp16 banks, 6CH each (3CH floats)
    short* A_ = (short*)(F + 2  * (size_t)CH);
    short* B_ = (short*)(F + 5  * (size_t)CH);
    short* C_ = (short*)(F + 8  * (size_t)CH);
    short* D_ = (short*)(F + 11 * (size_t)CH);
    float* F0  = F + 14 * (size_t)CH;    // 6 CH f32 (U)
    float* part = F + 20 * (size_t)CH;   // partials

    build_tables<<<1024, 256, 0, stream>>>(Mc, Ms, McT, GT);

    // d = s-t -> A (nat), B (transposed); + t / (1-m) partials
    diff_split_red<<<dim3(16, 16, 6), 256, 0, stream>>>(s, t, m, A_, B_,
                                                        part, part + 1536);

    // L1 fused: gx/gyT GEMMs + mask(+transpose) -> uxT (C), uyT (D)
    gemm_l1<<<dim3(8, 8, 12), 256, 0, stream>>>(A_, B_, GT, m, C_, D_);

    // L2: P = Mc~uxT -> A ; Q = Ms~uyT -> B
    gemm_tn<1><<<dim3(8, 8, 12), 256, 0, stream>>>(
        Mc, 0, C_, CH, nullptr, A_, CH,
        Ms, 0, D_, CH, nullptr, B_, CH, 6, nullptr, nullptr);

    // L3 fused: GxT = Ms~P & GyT = Mc~Q + napply -> npT (C)
    gemm_l3<<<dim3(8, 8, 6), 256, 0, stream>>>(Ms, Mc, A_, B_, C_);

    // L4: R = McT~npT -> D
    gemm_tn<1><<<dim3(8, 8, 6), 256, 0, stream>>>(
        McT, 0, C_, CH, nullptr, D_, CH,
        McT, 0, C_, CH, nullptr, D_, CH, 6, nullptr, nullptr);

    // L5: U = R~McT -> F0 + masked-dot partials
    gemm_tn<2><<<dim3(8, 8, 6), 256, 0, stream>>>(
        D_, CH, McT, 0, F0, nullptr, CH,
        D_, CH, McT, 0, F0, nullptr, CH, 6, m, part + 2304);

    // out = t + U + shift
    final_out<<<768, 256, 0, stream>>>(t, F0, part, out);
}